// Round 2
// baseline (1673.923 us; speedup 1.0000x reference)
//
#include <hip/hip_runtime.h>
#include <hip/hip_bf16.h>
#include <float.h>
#include <math.h>

#define Bz 8
#define Dd 256
#define Tt 2048
#define Kk 8192
#define Mm (Bz*Tt)          // 16384 rows (b*T + t)

#define NSPLIT 8            // K-direction split of the 8192 codes
#define MT 128              // rows per block
#define NT 128              // codes per n-tile
#define KT 8                // d-chunk staged in LDS
#define NTILES (Kk / NSPLIT / NT)   // 8 n-tiles per split

// Flag rows whose fast top-2 gap could be affected by the np reference's
// fp32 quantization at |d|~256 (ulp 3.05e-5) plus fast/BLAS noise.
#define RESCAN_MARGIN 1.2e-4f

static_assert(NTILES * NSPLIT * NT == Kk, "tiling must cover K");
static_assert(MT * (Mm / MT) == Mm, "tiling must cover M");

// ---------------------------------------------------------------------------
// numpy-faithful pairwise sum of squares (numpy pairwise_sum, blocksize 128):
// n=256 -> pairwise(a,128) + pairwise(a+128,128); n=128 -> 8-accumulator
// unrolled loop, combine ((r0+r1)+(r2+r3))+((r4+r5)+(r6+r7)).
// __fmul_rn/__fadd_rn prevent FMA contraction (np squares elementwise first).
// ---------------------------------------------------------------------------
__device__ __forceinline__ float np_sumsq128(const float* __restrict__ x) {
  float r0 = __fmul_rn(x[0], x[0]);
  float r1 = __fmul_rn(x[1], x[1]);
  float r2 = __fmul_rn(x[2], x[2]);
  float r3 = __fmul_rn(x[3], x[3]);
  float r4 = __fmul_rn(x[4], x[4]);
  float r5 = __fmul_rn(x[5], x[5]);
  float r6 = __fmul_rn(x[6], x[6]);
  float r7 = __fmul_rn(x[7], x[7]);
  for (int i = 8; i < 128; i += 8) {
    r0 = __fadd_rn(r0, __fmul_rn(x[i+0], x[i+0]));
    r1 = __fadd_rn(r1, __fmul_rn(x[i+1], x[i+1]));
    r2 = __fadd_rn(r2, __fmul_rn(x[i+2], x[i+2]));
    r3 = __fadd_rn(r3, __fmul_rn(x[i+3], x[i+3]));
    r4 = __fadd_rn(r4, __fmul_rn(x[i+4], x[i+4]));
    r5 = __fadd_rn(r5, __fmul_rn(x[i+5], x[i+5]));
    r6 = __fadd_rn(r6, __fmul_rn(x[i+6], x[i+6]));
    r7 = __fadd_rn(r7, __fmul_rn(x[i+7], x[i+7]));
  }
  return __fadd_rn(__fadd_rn(__fadd_rn(r0, r1), __fadd_rn(r2, r3)),
                   __fadd_rn(__fadd_rn(r4, r5), __fadd_rn(r6, r7)));
}
__device__ __forceinline__ float np_sumsq256(const float* __restrict__ x) {
  return __fadd_rn(np_sumsq128(x), np_sumsq128(x + 128));
}

// ---------------------------------------------------------------------------
// Kernel 1: faithful codebook norms C_k (numpy order); zero accumulators
// ---------------------------------------------------------------------------
__global__ void k_prep(const float* __restrict__ cb, float* __restrict__ sc,
                       double* __restrict__ loss_accum, int* __restrict__ rescan_cnt) {
  const int k = blockIdx.x * blockDim.x + threadIdx.x;
  if (k == 0) { *loss_accum = 0.0; *rescan_cnt = 0; }
  if (k < Kk) sc[k] = np_sumsq256(cb + (size_t)k * Dd);
}

// ---------------------------------------------------------------------------
// Kernel 2: fp32 fast score pass with per-row top-2 tracking.
// s_k = C_k - 2*dot(z_row, c_k)   (row-constant ||z||^2 omitted: gap-invariant)
// ---------------------------------------------------------------------------
__global__ __launch_bounds__(256, 2)
void k_argmin(const float* __restrict__ z, const float* __restrict__ cb,
              const float* __restrict__ sc,
              float* __restrict__ pd1, float* __restrict__ pd2, int* __restrict__ pi1) {
  __shared__ float As[KT][MT + 4];   // A: z tile, [d][row]
  __shared__ float Bs[KT][NT + 4];   // B: codebook tile, [d][col]
  __shared__ float rs1[MT][16];
  __shared__ float rs2[MT][16];
  __shared__ int   ri1[MT][16];

  const int tid = threadIdx.x;
  const int tx = tid & 15, ty = tid >> 4;
  const int rowtile = blockIdx.x & 127;
  const int split   = blockIdx.x >> 7;
  const int m0 = rowtile * MT;
  const int b  = m0 / Tt, t0 = m0 & (Tt - 1);
  const float* zb = z + (size_t)b * Dd * Tt + t0;   // zb[d*Tt + i] = z[b][d][t0+i]

  const int a_kk = tid >> 5, a_i4 = (tid & 31) * 4;   // A: 8 d-rows x 128 t
  const int b_j  = tid >> 1, b_q4 = (tid & 1) * 4;    // B: 128 codes x 8 d

  float s1[8], s2[8]; int i1[8];
  #pragma unroll
  for (int r = 0; r < 8; ++r) { s1[r] = INFINITY; s2[r] = INFINITY; i1[r] = 0x7fffffff; }

  for (int nt = 0; nt < NTILES; ++nt) {
    const int n0 = (split * NTILES + nt) * NT;
    float acc[8][8];
    #pragma unroll
    for (int r = 0; r < 8; ++r)
      #pragma unroll
      for (int c = 0; c < 8; ++c) acc[r][c] = 0.f;

    for (int kt = 0; kt < Dd / KT; ++kt) {
      const int d0 = kt * KT;
      const float4 av = *(const float4*)(zb + (size_t)(d0 + a_kk) * Tt + a_i4);
      const float4 bv = *(const float4*)(cb + (size_t)(n0 + b_j) * Dd + d0 + b_q4);
      __syncthreads();
      *(float4*)&As[a_kk][a_i4] = av;
      Bs[b_q4+0][b_j] = bv.x;
      Bs[b_q4+1][b_j] = bv.y;
      Bs[b_q4+2][b_j] = bv.z;
      Bs[b_q4+3][b_j] = bv.w;
      __syncthreads();
      #pragma unroll
      for (int kk = 0; kk < KT; ++kk) {
        float a[8], bb[8];
        *(float4*)&a[0]  = *(const float4*)&As[kk][ty*8];
        *(float4*)&a[4]  = *(const float4*)&As[kk][ty*8+4];
        *(float4*)&bb[0] = *(const float4*)&Bs[kk][tx*8];
        *(float4*)&bb[4] = *(const float4*)&Bs[kk][tx*8+4];
        #pragma unroll
        for (int r = 0; r < 8; ++r)
          #pragma unroll
          for (int c = 0; c < 8; ++c)
            acc[r][c] += a[r] * bb[c];
      }
    }
    #pragma unroll
    for (int r = 0; r < 8; ++r) {
      #pragma unroll
      for (int c = 0; c < 8; ++c) {
        const int k = n0 + tx*8 + c;
        const float s = fmaf(-2.0f, acc[r][c], sc[k]);
        if (s < s1[r]) { s2[r] = s1[r]; s1[r] = s; i1[r] = k; }
        else if (s < s2[r]) s2[r] = s;
      }
    }
  }

  __syncthreads();
  #pragma unroll
  for (int r = 0; r < 8; ++r) {
    rs1[ty*8 + r][tx] = s1[r];
    rs2[ty*8 + r][tx] = s2[r];
    ri1[ty*8 + r][tx] = i1[r];
  }
  __syncthreads();
  if (tid < MT) {
    float a1 = INFINITY, a2 = INFINITY; int ai = 0x7fffffff;
    for (int x = 0; x < 16; ++x) {
      const float b1 = rs1[tid][x], b2 = rs2[tid][x]; const int bi = ri1[tid][x];
      if (b1 < a1 || (b1 == a1 && bi < ai)) { a2 = fminf(a1, b2); a1 = b1; ai = bi; }
      else a2 = fminf(a2, b1);
    }
    const size_t o = (size_t)split * Mm + (size_t)(m0 + tid);
    pd1[o] = a1; pd2[o] = a2; pi1[o] = ai;
  }
}

// ---------------------------------------------------------------------------
// Kernel 3: combine the NSPLIT partials per row; flag near-ties for np rescan
// ---------------------------------------------------------------------------
__global__ void k_combine(const float* __restrict__ pd1, const float* __restrict__ pd2,
                          const int* __restrict__ pi1, int* __restrict__ idxf,
                          int* __restrict__ rescan_cnt, int* __restrict__ rlist,
                          float* __restrict__ outIdx) {
  const int m = blockIdx.x * blockDim.x + threadIdx.x;
  if (m >= Mm) return;
  float a1 = INFINITY, a2 = INFINITY; int ai = 0x7fffffff;
  #pragma unroll
  for (int spl = 0; spl < NSPLIT; ++spl) {
    const size_t o = (size_t)spl * Mm + m;
    const float b1 = pd1[o], b2 = pd2[o]; const int bi = pi1[o];
    if (b1 < a1 || (b1 == a1 && bi < ai)) { a2 = fminf(a1, b2); a1 = b1; ai = bi; }
    else a2 = fminf(a2, b1);
  }
  idxf[m]   = ai;
  outIdx[m] = (float)ai;
  if (a2 - a1 <= RESCAN_MARGIN) { const int p = atomicAdd(rescan_cnt, 1); rlist[p] = m; }
}

// ---------------------------------------------------------------------------
// Kernel 4: np-faithful rescan of flagged rows.
// d_k = fl32( fl32( A - 2*fl32(dot_f64) ) + C_k ), argmin first-index.
// A = np-pairwise sum of z_row^2; C_k = faithful sc[k]; dot in f64 (±1ulp of
// np's fp32 BLAS value).
// ---------------------------------------------------------------------------
__global__ void k_rescan(const float* __restrict__ z, const float* __restrict__ cb,
                         const float* __restrict__ sc,
                         const int* __restrict__ rescan_cnt, const int* __restrict__ rlist,
                         int* __restrict__ idxf, float* __restrict__ outIdx) {
  __shared__ float zrow[Dd];
  __shared__ float Ash;
  __shared__ float sval[256];
  __shared__ int   sidx[256];
  const int tid = threadIdx.x;
  const int cnt = *rescan_cnt;
  for (int it = blockIdx.x; it < cnt; it += gridDim.x) {
    const int m = rlist[it];
    const int b = m / Tt, t = m & (Tt - 1);
    __syncthreads();
    zrow[tid] = z[(size_t)b * Dd * Tt + (size_t)tid * Tt + t];
    __syncthreads();
    if (tid == 0) Ash = np_sumsq256(zrow);
    __syncthreads();
    const float A = Ash;
    float best = INFINITY; int bi = 0x7fffffff;
    for (int k = tid; k < Kk; k += 256) {
      const float* cr = cb + (size_t)k * Dd;
      double a0 = 0.0, a1 = 0.0, a2 = 0.0, a3 = 0.0;
      for (int d = 0; d < Dd; d += 4) {
        const float4 c4 = *(const float4*)(cr + d);
        a0 = fma((double)c4.x, (double)zrow[d+0], a0);
        a1 = fma((double)c4.y, (double)zrow[d+1], a1);
        a2 = fma((double)c4.z, (double)zrow[d+2], a2);
        a3 = fma((double)c4.w, (double)zrow[d+3], a3);
      }
      const float M  = (float)((a0 + a1) + (a2 + a3));
      const float t1 = __fsub_rn(A, __fmul_rn(2.0f, M));
      const float dq = __fadd_rn(t1, sc[k]);
      if (dq < best) { best = dq; bi = k; }     // ascending k -> first-min
    }
    sval[tid] = best; sidx[tid] = bi;
    __syncthreads();
    for (int off = 128; off; off >>= 1) {
      if (tid < off) {
        if (sval[tid+off] < sval[tid] ||
            (sval[tid+off] == sval[tid] && sidx[tid+off] < sidx[tid])) {
          sval[tid] = sval[tid+off]; sidx[tid] = sidx[tid+off];
        }
      }
      __syncthreads();
    }
    if (tid == 0) { idxf[m] = sidx[0]; outIdx[m] = (float)sidx[0]; }
    __syncthreads();
  }
}

// ---------------------------------------------------------------------------
// Kernel 5: gather z_q, write z_q_st = z + (z_q - z), accumulate loss sum
// ---------------------------------------------------------------------------
__global__ void k_epilogue(const float* __restrict__ z, const float* __restrict__ cb,
                           const int* __restrict__ idxf, float* __restrict__ outZ,
                           double* __restrict__ loss_accum) {
  const int g  = blockIdx.x * blockDim.x + threadIdx.x;
  const int e4 = g * 4;
  const int t4 = e4 & (Tt - 1);
  const int bd = e4 >> 11;
  const int d  = bd & (Dd - 1);
  const int b  = bd >> 8;
  const float4 zv = *(const float4*)(z + e4);
  const int mb = b * Tt + t4;
  const float q0 = cb[(size_t)idxf[mb+0] * Dd + d];
  const float q1 = cb[(size_t)idxf[mb+1] * Dd + d];
  const float q2 = cb[(size_t)idxf[mb+2] * Dd + d];
  const float q3 = cb[(size_t)idxf[mb+3] * Dd + d];
  const float r0 = q0 - zv.x, r1 = q1 - zv.y, r2 = q2 - zv.z, r3 = q3 - zv.w;
  float4 o;
  o.x = zv.x + r0; o.y = zv.y + r1; o.z = zv.z + r2; o.w = zv.w + r3;
  *(float4*)(outZ + e4) = o;
  double ls = (double)r0*r0 + (double)r1*r1 + (double)r2*r2 + (double)r3*r3;
  #pragma unroll
  for (int off = 32; off; off >>= 1) ls += __shfl_down(ls, off);
  if ((threadIdx.x & 63) == 0) atomicAdd(loss_accum, ls);
}

// ---------------------------------------------------------------------------
// Kernel 6: finalize loss = mean + 0.1*mean
// ---------------------------------------------------------------------------
__global__ void k_finalize(const double* __restrict__ loss_accum, float* __restrict__ outLoss) {
  const double mean = *loss_accum / (double)((size_t)Bz * Dd * Tt);
  *outLoss = (float)(mean + 0.1 * mean);
}

// ---------------------------------------------------------------------------
extern "C" void kernel_launch(void* const* d_in, const int* in_sizes, int n_in,
                              void* d_out, int out_size, void* d_ws, size_t ws_size,
                              hipStream_t stream) {
  (void)in_sizes; (void)n_in; (void)out_size; (void)ws_size;
  const float* z  = (const float*)d_in[0];   // (B, D, T) fp32
  const float* cb = (const float*)d_in[1];   // (K, D)    fp32

  float* outZ    = (float*)d_out;                     // (B, D, T)
  float* outIdx  = outZ + (size_t)Bz * Dd * Tt;       // (B, T) as float
  float* outLoss = outIdx + Mm;                       // scalar

  char* w = (char*)d_ws;
  double* loss_accum = (double*)w;            w += 16;
  int*    rescan_cnt = (int*)w;               w += 16;
  int*    rlist      = (int*)w;               w += sizeof(int)   * Mm;
  int*    idxf       = (int*)w;               w += sizeof(int)   * Mm;
  float*  sc         = (float*)w;             w += sizeof(float) * Kk;
  float*  pd1        = (float*)w;             w += sizeof(float) * NSPLIT * Mm;
  float*  pd2        = (float*)w;             w += sizeof(float) * NSPLIT * Mm;
  int*    pi1        = (int*)w;               /* total < 2 MB */

  k_prep    <<<dim3(Kk / 256), 256, 0, stream>>>(cb, sc, loss_accum, rescan_cnt);
  k_argmin  <<<dim3(NSPLIT * (Mm / MT)), 256, 0, stream>>>(z, cb, sc, pd1, pd2, pi1);
  k_combine <<<dim3(Mm / 256), 256, 0, stream>>>(pd1, pd2, pi1, idxf, rescan_cnt, rlist, outIdx);
  k_rescan  <<<dim3(64), 256, 0, stream>>>(z, cb, sc, rescan_cnt, rlist, idxf, outIdx);
  k_epilogue<<<dim3(((size_t)Mm * Dd / 4) / 256), 256, 0, stream>>>(z, cb, idxf, outZ, loss_accum);
  k_finalize<<<dim3(1), 1, 0, stream>>>(loss_accum, outLoss);
}

// Round 3
// 1193.163 us; speedup vs baseline: 1.4029x; 1.4029x over previous
//
#include <hip/hip_runtime.h>
#include <hip/hip_bf16.h>
#include <float.h>
#include <math.h>

#define Bz 8
#define Dd 256
#define Tt 2048
#define Kk 8192
#define Mm (Bz*Tt)          // 16384 rows (b*T + t)

// MFMA scorer tiling
#define BM 128
#define BN 128
#define BK 64
#define NSPL (Kk/BN)        // 64 column splits
#define AS_STRIDE (BK+8)    // f16 units; 144 B row stride -> <=2-way LDS conflicts (free)

// Margin: covers f16 fast-pass score error (~12 sigma) + np fp32 quantization straddle
#define RESCAN_MARGIN 6e-4f

typedef __attribute__((ext_vector_type(8))) _Float16 f16x8;
typedef __attribute__((ext_vector_type(4))) float    f32x4;

// ---------------------------------------------------------------------------
// numpy-faithful pairwise sum of squares (blocksize-128 pairwise, 8 accums)
// ---------------------------------------------------------------------------
__device__ __forceinline__ float np_sumsq128(const float* __restrict__ x) {
  float r0 = __fmul_rn(x[0], x[0]);
  float r1 = __fmul_rn(x[1], x[1]);
  float r2 = __fmul_rn(x[2], x[2]);
  float r3 = __fmul_rn(x[3], x[3]);
  float r4 = __fmul_rn(x[4], x[4]);
  float r5 = __fmul_rn(x[5], x[5]);
  float r6 = __fmul_rn(x[6], x[6]);
  float r7 = __fmul_rn(x[7], x[7]);
  for (int i = 8; i < 128; i += 8) {
    r0 = __fadd_rn(r0, __fmul_rn(x[i+0], x[i+0]));
    r1 = __fadd_rn(r1, __fmul_rn(x[i+1], x[i+1]));
    r2 = __fadd_rn(r2, __fmul_rn(x[i+2], x[i+2]));
    r3 = __fadd_rn(r3, __fmul_rn(x[i+3], x[i+3]));
    r4 = __fadd_rn(r4, __fmul_rn(x[i+4], x[i+4]));
    r5 = __fadd_rn(r5, __fmul_rn(x[i+5], x[i+5]));
    r6 = __fadd_rn(r6, __fmul_rn(x[i+6], x[i+6]));
    r7 = __fadd_rn(r7, __fmul_rn(x[i+7], x[i+7]));
  }
  return __fadd_rn(__fadd_rn(__fadd_rn(r0, r1), __fadd_rn(r2, r3)),
                   __fadd_rn(__fadd_rn(r4, r5), __fadd_rn(r6, r7)));
}
__device__ __forceinline__ float np_sumsq256(const float* __restrict__ x) {
  return __fadd_rn(np_sumsq128(x), np_sumsq128(x + 128));
}

// ---------------------------------------------------------------------------
// Kernel: transpose-cast z (B,D,T) f32 -> Ah (M, D) f16   (Ah[b*T+t][d])
// ---------------------------------------------------------------------------
__global__ void k_cast_z(const float* __restrict__ z, _Float16* __restrict__ Ah) {
  __shared__ _Float16 tile[64][64 + 8];   // [t][d]
  const int tid = threadIdx.x;
  const int bidx = blockIdx.x;            // 8 * 4 * 32 = 1024
  const int b  = bidx >> 7;
  const int dt = (bidx >> 5) & 3;
  const int tt = bidx & 31;
  const int d0 = dt * 64, t0 = tt * 64;
  const float* zb = z + ((size_t)b * Dd + d0) * Tt + t0;
  #pragma unroll
  for (int p = 0; p < 4; ++p) {
    const int d  = p * 16 + (tid >> 4);
    const int tl = (tid & 15) * 4;
    const float4 v = *(const float4*)(zb + (size_t)d * Tt + tl);
    tile[tl+0][d] = (_Float16)v.x;
    tile[tl+1][d] = (_Float16)v.y;
    tile[tl+2][d] = (_Float16)v.z;
    tile[tl+3][d] = (_Float16)v.w;
  }
  __syncthreads();
  const int r = tid >> 2, seg = tid & 3;
  const int m = b * Tt + t0 + r;
  int4* dst = (int4*)(Ah + (size_t)m * Dd + d0 + seg * 16);
  const int4* srcv = (const int4*)(&tile[r][seg * 16]);
  dst[0] = srcv[0];
  dst[1] = srcv[1];
}

// ---------------------------------------------------------------------------
// Kernel: cast codebook f32 -> f16, prescaled by 256 (avoids f16 subnormals)
// ---------------------------------------------------------------------------
__global__ void k_cast_cb(const float* __restrict__ cb, _Float16* __restrict__ Bh) {
  const size_t g = (size_t)blockIdx.x * blockDim.x + threadIdx.x;  // per 8 elems
  const float4 v0 = *(const float4*)(cb + g * 8);
  const float4 v1 = *(const float4*)(cb + g * 8 + 4);
  f16x8 o;
  o[0] = (_Float16)(v0.x * 256.f); o[1] = (_Float16)(v0.y * 256.f);
  o[2] = (_Float16)(v0.z * 256.f); o[3] = (_Float16)(v0.w * 256.f);
  o[4] = (_Float16)(v1.x * 256.f); o[5] = (_Float16)(v1.y * 256.f);
  o[6] = (_Float16)(v1.z * 256.f); o[7] = (_Float16)(v1.w * 256.f);
  *(f16x8*)(Bh + g * 8) = o;
}

// ---------------------------------------------------------------------------
// Kernel: np-faithful codebook norms; zero accumulators
// ---------------------------------------------------------------------------
__global__ void k_prep(const float* __restrict__ cb, float* __restrict__ sc,
                       double* __restrict__ loss_accum, int* __restrict__ rescan_cnt) {
  const int k = blockIdx.x * blockDim.x + threadIdx.x;
  if (k == 0) { *loss_accum = 0.0; *rescan_cnt = 0; }
  if (k < Kk) sc[k] = np_sumsq256(cb + (size_t)k * Dd);
}

// ---------------------------------------------------------------------------
// Kernel: f16 MFMA score pass, fused per-row top-2 over the 128-code column.
// s_k = sc[k] - (2/256) * mfma_dot(zh, 256*ch)
// ---------------------------------------------------------------------------
__global__ __launch_bounds__(256, 2)
void k_mfma(const _Float16* __restrict__ Ah, const _Float16* __restrict__ Bh,
            const float* __restrict__ sc,
            float* __restrict__ pd1, float* __restrict__ pd2, int* __restrict__ pi1) {
  __shared__ __align__(16) _Float16 smem[2][BM * AS_STRIDE];  // A, B: 36864 B
  _Float16* As = &smem[0][0];
  _Float16* Bs = &smem[1][0];

  const int tid  = threadIdx.x;
  const int bx   = blockIdx.x & (NSPL - 1);
  const int by   = blockIdx.x >> 6;
  const int m0   = by * BM, n0 = bx * BN;
  const int w    = tid >> 6, lane = tid & 63;
  const int wy   = w >> 1, wx = w & 1;
  const int l15  = lane & 15, quad = lane >> 4;

  const int srow = tid >> 1, sseg = tid & 1;   // staging: 2 thr/row, 32 f16 each
  const _Float16* gA = Ah + (size_t)(m0 + srow) * Dd + sseg * 32;
  const _Float16* gB = Bh + (size_t)(n0 + srow) * Dd + sseg * 32;
  _Float16* wAp = As + srow * AS_STRIDE + sseg * 32;
  _Float16* wBp = Bs + srow * AS_STRIDE + sseg * 32;

  f32x4 acc[4][4];
  #pragma unroll
  for (int mi = 0; mi < 4; ++mi)
    #pragma unroll
    for (int ni = 0; ni < 4; ++ni)
      acc[mi][ni] = (f32x4){0.f, 0.f, 0.f, 0.f};

  float scv[4];
  #pragma unroll
  for (int ni = 0; ni < 4; ++ni) scv[ni] = sc[n0 + wx * 64 + ni * 16 + l15];

  for (int kc = 0; kc < Dd; kc += BK) {
    int4 ra[4], rb[4];
    #pragma unroll
    for (int i = 0; i < 4; ++i) {
      ra[i] = *(const int4*)(gA + kc + i * 8);
      rb[i] = *(const int4*)(gB + kc + i * 8);
    }
    __syncthreads();
    #pragma unroll
    for (int i = 0; i < 4; ++i) {
      *(int4*)(wAp + i * 8) = ra[i];
      *(int4*)(wBp + i * 8) = rb[i];
    }
    __syncthreads();
    #pragma unroll
    for (int ks = 0; ks < 2; ++ks) {
      f16x8 af[4], bf[4];
      #pragma unroll
      for (int mi = 0; mi < 4; ++mi)
        af[mi] = *(const f16x8*)(As + (wy*64 + mi*16 + l15) * AS_STRIDE + ks*32 + quad*8);
      #pragma unroll
      for (int ni = 0; ni < 4; ++ni)
        bf[ni] = *(const f16x8*)(Bs + (wx*64 + ni*16 + l15) * AS_STRIDE + ks*32 + quad*8);
      #pragma unroll
      for (int mi = 0; mi < 4; ++mi)
        #pragma unroll
        for (int ni = 0; ni < 4; ++ni)
          acc[mi][ni] = __builtin_amdgcn_mfma_f32_16x16x32_f16(af[mi], bf[ni], acc[mi][ni], 0, 0, 0);
    }
  }

  // ---- epilogue: per-row top-2 ----
  // C/D layout: n(col) = lane&15, m(row-in-frag) = quad*4 + reg
  float s1[16], s2[16]; int i1[16];
  #pragma unroll
  for (int mi = 0; mi < 4; ++mi)
    #pragma unroll
    for (int r = 0; r < 4; ++r) {
      const int q = mi * 4 + r;
      float a1 = INFINITY, a2 = INFINITY; int ai = 0x7fffffff;
      #pragma unroll
      for (int ni = 0; ni < 4; ++ni) {
        const float s = fmaf(-0.0078125f, acc[mi][ni][r], scv[ni]);  // -2/256
        const int   k = n0 + wx * 64 + ni * 16 + l15;
        if (s < a1) { a2 = a1; a1 = s; ai = k; }
        else if (s < a2) a2 = s;
      }
      s1[q] = a1; s2[q] = a2; i1[q] = ai;
    }
  // merge across the 16 lanes of each quad (same rows, different n)
  #pragma unroll
  for (int off = 1; off <= 8; off <<= 1) {
    #pragma unroll
    for (int q = 0; q < 16; ++q) {
      const float o1 = __shfl_xor(s1[q], off);
      const float o2 = __shfl_xor(s2[q], off);
      const int   oi = __shfl_xor(i1[q], off);
      if (o1 < s1[q] || (o1 == s1[q] && oi < i1[q])) {
        s2[q] = fminf(s1[q], o2); s1[q] = o1; i1[q] = oi;
      } else s2[q] = fminf(s2[q], o1);
    }
  }

  // cross-wave (wx) merge through LDS (reuse smem)
  float* red1 = (float*)&smem[0][0];
  float* red2 = red1 + 256;
  int*   redi = (int*)(red1 + 512);
  __syncthreads();
  if (l15 == 0) {
    #pragma unroll
    for (int mi = 0; mi < 4; ++mi)
      #pragma unroll
      for (int r = 0; r < 4; ++r) {
        const int q  = mi * 4 + r;
        const int ml = wy * 64 + mi * 16 + quad * 4 + r;
        red1[ml * 2 + wx] = s1[q];
        red2[ml * 2 + wx] = s2[q];
        redi[ml * 2 + wx] = i1[q];
      }
  }
  __syncthreads();
  if (tid < BM) {
    float a1 = red1[tid * 2], a2 = red2[tid * 2]; int ai = redi[tid * 2];
    const float b1 = red1[tid * 2 + 1], b2 = red2[tid * 2 + 1];
    const int   bi = redi[tid * 2 + 1];
    if (b1 < a1) { a2 = fminf(a1, b2); a1 = b1; ai = bi; }   // wx=1 ks are larger
    else a2 = fminf(a2, b1);
    const size_t o = (size_t)bx * Mm + (size_t)(m0 + tid);
    pd1[o] = a1; pd2[o] = a2; pi1[o] = ai;
  }
}

// ---------------------------------------------------------------------------
// Kernel: combine the NSPL partials per row; flag near-ties for np rescan
// ---------------------------------------------------------------------------
__global__ void k_combine(const float* __restrict__ pd1, const float* __restrict__ pd2,
                          const int* __restrict__ pi1, int* __restrict__ idxf,
                          int* __restrict__ rescan_cnt, int* __restrict__ rlist,
                          float* __restrict__ outIdx) {
  const int m = blockIdx.x * blockDim.x + threadIdx.x;
  if (m >= Mm) return;
  float a1 = INFINITY, a2 = INFINITY; int ai = 0x7fffffff;
  for (int spl = 0; spl < NSPL; ++spl) {
    const size_t o = (size_t)spl * Mm + m;
    const float b1 = pd1[o], b2 = pd2[o]; const int bi = pi1[o];
    if (b1 < a1) { a2 = fminf(a1, b2); a1 = b1; ai = bi; }   // splits ascend in k
    else a2 = fminf(a2, b1);
  }
  idxf[m]   = ai;
  outIdx[m] = (float)ai;
  if (a2 - a1 <= RESCAN_MARGIN) { const int p = atomicAdd(rescan_cnt, 1); rlist[p] = m; }
}

// ---------------------------------------------------------------------------
// Kernel: np-faithful rescan of flagged rows (f64 dot -> fp32, np assoc order)
// ---------------------------------------------------------------------------
__global__ void k_rescan(const float* __restrict__ z, const float* __restrict__ cb,
                         const float* __restrict__ sc,
                         const int* __restrict__ rescan_cnt, const int* __restrict__ rlist,
                         int* __restrict__ idxf, float* __restrict__ outIdx) {
  __shared__ float zrow[Dd];
  __shared__ float Ash;
  __shared__ float sval[256];
  __shared__ int   sidx[256];
  const int tid = threadIdx.x;
  const int cnt = *rescan_cnt;
  for (int it = blockIdx.x; it < cnt; it += gridDim.x) {
    const int m = rlist[it];
    const int b = m / Tt, t = m & (Tt - 1);
    __syncthreads();
    zrow[tid] = z[(size_t)b * Dd * Tt + (size_t)tid * Tt + t];
    __syncthreads();
    if (tid == 0) Ash = np_sumsq256(zrow);
    __syncthreads();
    const float A = Ash;
    float best = INFINITY; int bi = 0x7fffffff;
    for (int k = tid; k < Kk; k += 256) {
      const float* cr = cb + (size_t)k * Dd;
      double a0 = 0.0, a1 = 0.0, a2 = 0.0, a3 = 0.0;
      for (int d = 0; d < Dd; d += 4) {
        const float4 c4 = *(const float4*)(cr + d);
        a0 = fma((double)c4.x, (double)zrow[d+0], a0);
        a1 = fma((double)c4.y, (double)zrow[d+1], a1);
        a2 = fma((double)c4.z, (double)zrow[d+2], a2);
        a3 = fma((double)c4.w, (double)zrow[d+3], a3);
      }
      const float M  = (float)((a0 + a1) + (a2 + a3));
      const float t1 = __fsub_rn(A, __fmul_rn(2.0f, M));
      const float dq = __fadd_rn(t1, sc[k]);
      if (dq < best) { best = dq; bi = k; }     // ascending k -> first-min
    }
    sval[tid] = best; sidx[tid] = bi;
    __syncthreads();
    for (int off = 128; off; off >>= 1) {
      if (tid < off) {
        if (sval[tid+off] < sval[tid] ||
            (sval[tid+off] == sval[tid] && sidx[tid+off] < sidx[tid])) {
          sval[tid] = sval[tid+off]; sidx[tid] = sidx[tid+off];
        }
      }
      __syncthreads();
    }
    if (tid == 0) { idxf[m] = sidx[0]; outIdx[m] = (float)sidx[0]; }
    __syncthreads();
  }
}

// ---------------------------------------------------------------------------
// Kernel: gather z_q, write z_q_st, accumulate loss sum
// ---------------------------------------------------------------------------
__global__ void k_epilogue(const float* __restrict__ z, const float* __restrict__ cb,
                           const int* __restrict__ idxf, float* __restrict__ outZ,
                           double* __restrict__ loss_accum) {
  const int g  = blockIdx.x * blockDim.x + threadIdx.x;
  const int e4 = g * 4;
  const int t4 = e4 & (Tt - 1);
  const int bd = e4 >> 11;
  const int d  = bd & (Dd - 1);
  const int b  = bd >> 8;
  const float4 zv = *(const float4*)(z + e4);
  const int mb = b * Tt + t4;
  const float q0 = cb[(size_t)idxf[mb+0] * Dd + d];
  const float q1 = cb[(size_t)idxf[mb+1] * Dd + d];
  const float q2 = cb[(size_t)idxf[mb+2] * Dd + d];
  const float q3 = cb[(size_t)idxf[mb+3] * Dd + d];
  const float r0 = q0 - zv.x, r1 = q1 - zv.y, r2 = q2 - zv.z, r3 = q3 - zv.w;
  float4 o;
  o.x = zv.x + r0; o.y = zv.y + r1; o.z = zv.z + r2; o.w = zv.w + r3;
  *(float4*)(outZ + e4) = o;
  double ls = (double)r0*r0 + (double)r1*r1 + (double)r2*r2 + (double)r3*r3;
  #pragma unroll
  for (int off = 32; off; off >>= 1) ls += __shfl_down(ls, off);
  if ((threadIdx.x & 63) == 0) atomicAdd(loss_accum, ls);
}

__global__ void k_finalize(const double* __restrict__ loss_accum, float* __restrict__ outLoss) {
  const double mean = *loss_accum / (double)((size_t)Bz * Dd * Tt);
  *outLoss = (float)(mean + 0.1 * mean);
}

// ---------------------------------------------------------------------------
extern "C" void kernel_launch(void* const* d_in, const int* in_sizes, int n_in,
                              void* d_out, int out_size, void* d_ws, size_t ws_size,
                              hipStream_t stream) {
  (void)in_sizes; (void)n_in; (void)out_size; (void)ws_size;
  const float* z  = (const float*)d_in[0];   // (B, D, T) fp32
  const float* cb = (const float*)d_in[1];   // (K, D)    fp32

  float* outZ    = (float*)d_out;
  float* outIdx  = outZ + (size_t)Bz * Dd * Tt;
  float* outLoss = outIdx + Mm;

  char* w = (char*)d_ws;
  double*    loss_accum = (double*)w;    w += 16;
  int*       rescan_cnt = (int*)w;       w += 16;
  int*       rlist      = (int*)w;       w += sizeof(int)   * Mm;
  int*       idxf       = (int*)w;       w += sizeof(int)   * Mm;
  float*     sc         = (float*)w;     w += sizeof(float) * Kk;
  _Float16*  Ah         = (_Float16*)w;  w += sizeof(_Float16) * (size_t)Mm * Dd;
  _Float16*  Bh         = (_Float16*)w;  w += sizeof(_Float16) * (size_t)Kk * Dd;
  float*     pd1        = (float*)w;     w += sizeof(float) * (size_t)NSPL * Mm;
  float*     pd2        = (float*)w;     w += sizeof(float) * (size_t)NSPL * Mm;
  int*       pi1        = (int*)w;       /* total ~25.5 MB */

  k_cast_z  <<<dim3(1024), 256, 0, stream>>>(z, Ah);
  k_cast_cb <<<dim3((Kk * Dd / 8) / 256), 256, 0, stream>>>(cb, Bh);
  k_prep    <<<dim3(Kk / 256), 256, 0, stream>>>(cb, sc, loss_accum, rescan_cnt);
  k_mfma    <<<dim3((Mm / BM) * NSPL), 256, 0, stream>>>(Ah, Bh, sc, pd1, pd2, pi1);
  k_combine <<<dim3(Mm / 256), 256, 0, stream>>>(pd1, pd2, pi1, idxf, rescan_cnt, rlist, outIdx);
  k_rescan  <<<dim3(512), 256, 0, stream>>>(z, cb, sc, rescan_cnt, rlist, idxf, outIdx);
  k_epilogue<<<dim3(((size_t)Mm * Dd / 4) / 256), 256, 0, stream>>>(z, cb, idxf, outZ, loss_accum);
  k_finalize<<<dim3(1), 1, 0, stream>>>(loss_accum, outLoss);
}

// Round 4
// 915.239 us; speedup vs baseline: 1.8289x; 1.3037x over previous
//
#include <hip/hip_runtime.h>
#include <hip/hip_bf16.h>
#include <float.h>
#include <math.h>

#define Bz 8
#define Dd 256
#define Tt 2048
#define Kk 8192
#define Mm (Bz*Tt)          // 16384 rows (b*T + t)

// Scorer tiling: block = 128 rows x 1024 codes (8 n-tiles of 128), 512 threads
#define NSPL 8
#define BS_STRIDE 72        // f16 units; 144 B row stride -> uniform bank spread

// Rescan chunking
#define CHK 32              // codes per chunk block
#define GRP 16              // row groups
#define ZG_CAP 8192         // max flagged rows handled by fast rescan

// Margin: covers f16 fast-pass score error (~30 sigma) + np fp32 quantization straddle
#define RESCAN_MARGIN 6e-4f

typedef __attribute__((ext_vector_type(8))) _Float16 f16x8;
typedef __attribute__((ext_vector_type(4))) float    f32x4;

// ---------------------------------------------------------------------------
// numpy-faithful pairwise sum of squares (blocksize-128 pairwise, 8 accums)
// ---------------------------------------------------------------------------
__device__ __forceinline__ float np_sumsq128(const float* __restrict__ x) {
  float r0 = __fmul_rn(x[0], x[0]);
  float r1 = __fmul_rn(x[1], x[1]);
  float r2 = __fmul_rn(x[2], x[2]);
  float r3 = __fmul_rn(x[3], x[3]);
  float r4 = __fmul_rn(x[4], x[4]);
  float r5 = __fmul_rn(x[5], x[5]);
  float r6 = __fmul_rn(x[6], x[6]);
  float r7 = __fmul_rn(x[7], x[7]);
  for (int i = 8; i < 128; i += 8) {
    r0 = __fadd_rn(r0, __fmul_rn(x[i+0], x[i+0]));
    r1 = __fadd_rn(r1, __fmul_rn(x[i+1], x[i+1]));
    r2 = __fadd_rn(r2, __fmul_rn(x[i+2], x[i+2]));
    r3 = __fadd_rn(r3, __fmul_rn(x[i+3], x[i+3]));
    r4 = __fadd_rn(r4, __fmul_rn(x[i+4], x[i+4]));
    r5 = __fadd_rn(r5, __fmul_rn(x[i+5], x[i+5]));
    r6 = __fadd_rn(r6, __fmul_rn(x[i+6], x[i+6]));
    r7 = __fadd_rn(r7, __fmul_rn(x[i+7], x[i+7]));
  }
  return __fadd_rn(__fadd_rn(__fadd_rn(r0, r1), __fadd_rn(r2, r3)),
                   __fadd_rn(__fadd_rn(r4, r5), __fadd_rn(r6, r7)));
}
__device__ __forceinline__ float np_sumsq256(const float* __restrict__ x) {
  return __fadd_rn(np_sumsq128(x), np_sumsq128(x + 128));
}

// ---------------------------------------------------------------------------
// transpose-cast z (B,D,T) f32 -> Ah (M, D) f16
// ---------------------------------------------------------------------------
__global__ void k_cast_z(const float* __restrict__ z, _Float16* __restrict__ Ah) {
  __shared__ _Float16 tile[64][64 + 8];
  const int tid = threadIdx.x;
  const int bidx = blockIdx.x;            // 8 * 4 * 32 = 1024
  const int b  = bidx >> 7;
  const int dt = (bidx >> 5) & 3;
  const int tt = bidx & 31;
  const int d0 = dt * 64, t0 = tt * 64;
  const float* zb = z + ((size_t)b * Dd + d0) * Tt + t0;
  #pragma unroll
  for (int p = 0; p < 4; ++p) {
    const int d  = p * 16 + (tid >> 4);
    const int tl = (tid & 15) * 4;
    const float4 v = *(const float4*)(zb + (size_t)d * Tt + tl);
    tile[tl+0][d] = (_Float16)v.x;
    tile[tl+1][d] = (_Float16)v.y;
    tile[tl+2][d] = (_Float16)v.z;
    tile[tl+3][d] = (_Float16)v.w;
  }
  __syncthreads();
  const int r = tid >> 2, seg = tid & 3;
  const int m = b * Tt + t0 + r;
  int4* dst = (int4*)(Ah + (size_t)m * Dd + d0 + seg * 16);
  const int4* srcv = (const int4*)(&tile[r][seg * 16]);
  dst[0] = srcv[0];
  dst[1] = srcv[1];
}

// ---------------------------------------------------------------------------
// cast codebook f32 -> f16, prescaled by 256 (avoids f16 subnormals)
// ---------------------------------------------------------------------------
__global__ void k_cast_cb(const float* __restrict__ cb, _Float16* __restrict__ Bh) {
  const size_t g = (size_t)blockIdx.x * blockDim.x + threadIdx.x;
  const float4 v0 = *(const float4*)(cb + g * 8);
  const float4 v1 = *(const float4*)(cb + g * 8 + 4);
  f16x8 o;
  o[0] = (_Float16)(v0.x * 256.f); o[1] = (_Float16)(v0.y * 256.f);
  o[2] = (_Float16)(v0.z * 256.f); o[3] = (_Float16)(v0.w * 256.f);
  o[4] = (_Float16)(v1.x * 256.f); o[5] = (_Float16)(v1.y * 256.f);
  o[6] = (_Float16)(v1.z * 256.f); o[7] = (_Float16)(v1.w * 256.f);
  *(f16x8*)(Bh + g * 8) = o;
}

// ---------------------------------------------------------------------------
// np-faithful codebook norms; zero accumulators
// ---------------------------------------------------------------------------
__global__ void k_prep(const float* __restrict__ cb, float* __restrict__ sc,
                       double* __restrict__ loss_accum, int* __restrict__ rescan_cnt) {
  const int k = blockIdx.x * blockDim.x + threadIdx.x;
  if (k == 0) { *loss_accum = 0.0; *rescan_cnt = 0; }
  if (k < Kk) sc[k] = np_sumsq256(cb + (size_t)k * Dd);
}

// ---------------------------------------------------------------------------
// f16 MFMA score pass v3: 512 threads, A in registers (full K), B LDS dbuf.
// Block: 128 rows x 1024 codes; 8 waves in 4(m) x 2(n) grid, wave-tile 32x64.
// ---------------------------------------------------------------------------
__global__ __launch_bounds__(512, 2)
void k_mfma(const _Float16* __restrict__ Ah, const _Float16* __restrict__ Bh,
            const float* __restrict__ sc,
            float* __restrict__ pd1, float* __restrict__ pd2, int* __restrict__ pi1) {
  __shared__ __align__(16) _Float16 Bs[2][128 * BS_STRIDE];   // 36,864 B

  const int tid  = threadIdx.x;
  const int bx   = blockIdx.x >> 7;     // split 0..7  (1024 codes each)
  const int by   = blockIdx.x & 127;    // m-tile
  const int m0   = by * 128, n0 = bx * 1024;
  const int w    = tid >> 6, lane = tid & 63;
  const int wy   = w >> 1, wx = w & 1;
  const int l15  = lane & 15, quad = lane >> 4;

  // ---- A fragments in registers: full K for 2 row-frags (wave-tile 32 rows)
  f16x8 af[4][2][2];                    // [kc][ks][mi]
  {
    const _Float16* Abase = Ah + (size_t)(m0 + wy * 32 + l15) * Dd + quad * 8;
    #pragma unroll
    for (int kc = 0; kc < 4; ++kc)
      #pragma unroll
      for (int ks = 0; ks < 2; ++ks)
        #pragma unroll
        for (int mi = 0; mi < 2; ++mi)
          af[kc][ks][mi] = *(const f16x8*)(Abase + (size_t)mi * 16 * Dd + kc * 64 + ks * 32);
  }

  // ---- B staging: 512 threads, 16 f16 (32 B) each per chunk
  const int srow = tid >> 2, sseg = tid & 3;
  _Float16* wB = &Bs[0][0] + srow * BS_STRIDE + sseg * 16;

  int4 rb0[2], rb1[2];
  #define LOADB(sidx, r) { \
    const _Float16* p = Bh + (size_t)(n0 + ((sidx) >> 2) * 128 + srow) * Dd + ((sidx) & 3) * 64 + sseg * 16; \
    r[0] = *(const int4*)p; r[1] = *(const int4*)(p + 8); }

  LOADB(0, rb0);
  LOADB(1, rb1);

  f32x4 acc[2][4];
  #pragma unroll
  for (int mi = 0; mi < 2; ++mi)
    #pragma unroll
    for (int ni = 0; ni < 4; ++ni)
      acc[mi][ni] = (f32x4){0.f, 0.f, 0.f, 0.f};

  float s1[8], s2[8]; int i1[8];
  #pragma unroll
  for (int q = 0; q < 8; ++q) { s1[q] = INFINITY; s2[q] = INFINITY; i1[q] = 0x7fffffff; }

  float scv[4];

  for (int s = 0; s < 32; ++s) {        // s = nt*4 + kc
    const int buf = s & 1;
    __syncthreads();                    // all reads of Bs[buf] (step s-2) done
    {
      _Float16* d = wB + buf * (128 * BS_STRIDE);
      int4* r = buf ? rb1 : rb0;
      *(int4*)d = r[0];
      *(int4*)(d + 8) = r[1];
    }
    __syncthreads();
    if (s + 2 < 32) { if (buf) { LOADB(s + 2, rb1); } else { LOADB(s + 2, rb0); } }
    if ((s & 3) == 0) {
      const int nt = s >> 2;
      #pragma unroll
      for (int ni = 0; ni < 4; ++ni)
        scv[ni] = sc[n0 + nt * 128 + wx * 64 + ni * 16 + l15];
    }
    const int kc = s & 3;
    #pragma unroll
    for (int ks = 0; ks < 2; ++ks) {
      f16x8 bf[4];
      #pragma unroll
      for (int ni = 0; ni < 4; ++ni)
        bf[ni] = *(const f16x8*)(&Bs[buf][0] + (wx * 64 + ni * 16 + l15) * BS_STRIDE + ks * 32 + quad * 8);
      #pragma unroll
      for (int mi = 0; mi < 2; ++mi)
        #pragma unroll
        for (int ni = 0; ni < 4; ++ni)
          acc[mi][ni] = __builtin_amdgcn_mfma_f32_16x16x32_f16(af[kc][ks][mi], bf[ni], acc[mi][ni], 0, 0, 0);
    }
    if ((s & 3) == 3) {                 // fold n-tile into per-thread top-2
      const int nt = s >> 2;
      #pragma unroll
      for (int mi = 0; mi < 2; ++mi)
        #pragma unroll
        for (int r = 0; r < 4; ++r) {
          const int q = mi * 4 + r;
          #pragma unroll
          for (int ni = 0; ni < 4; ++ni) {
            const float sv = fmaf(-0.0078125f, acc[mi][ni][r], scv[ni]);  // -2/256
            const int   k  = n0 + nt * 128 + wx * 64 + ni * 16 + l15;
            if (sv < s1[q]) { s2[q] = s1[q]; s1[q] = sv; i1[q] = k; }
            else if (sv < s2[q]) s2[q] = sv;
            acc[mi][ni][r] = 0.f;
          }
        }
    }
  }

  // ---- merge across the 16 lanes of each quad-row-group
  #pragma unroll
  for (int off = 1; off <= 8; off <<= 1)
    #pragma unroll
    for (int q = 0; q < 8; ++q) {
      const float o1 = __shfl_xor(s1[q], off);
      const float o2 = __shfl_xor(s2[q], off);
      const int   oi = __shfl_xor(i1[q], off);
      if (o1 < s1[q] || (o1 == s1[q] && oi < i1[q])) {
        s2[q] = fminf(s1[q], o2); s1[q] = o1; i1[q] = oi;
      } else s2[q] = fminf(s2[q], o1);
    }

  // ---- cross-wave (wx) merge through LDS
  __syncthreads();
  float* red1 = (float*)&Bs[0][0];
  float* red2 = red1 + 256;
  int*   redi = (int*)(red1 + 512);
  if (l15 == 0) {
    #pragma unroll
    for (int mi = 0; mi < 2; ++mi)
      #pragma unroll
      for (int r = 0; r < 4; ++r) {
        const int q  = mi * 4 + r;
        const int ml = wy * 32 + mi * 16 + quad * 4 + r;
        red1[ml * 2 + wx] = s1[q];
        red2[ml * 2 + wx] = s2[q];
        redi[ml * 2 + wx] = i1[q];
      }
  }
  __syncthreads();
  if (tid < 128) {
    float a1 = red1[tid * 2], a2 = red2[tid * 2]; int ai = redi[tid * 2];
    const float b1 = red1[tid * 2 + 1], b2 = red2[tid * 2 + 1];
    const int   bi = redi[tid * 2 + 1];
    if (b1 < a1 || (b1 == a1 && bi < ai)) { a2 = fminf(a1, b2); a1 = b1; ai = bi; }
    else a2 = fminf(a2, b1);
    const size_t o = (size_t)bx * Mm + (size_t)(m0 + tid);
    pd1[o] = a1; pd2[o] = a2; pi1[o] = ai;
  }
}

// ---------------------------------------------------------------------------
// combine the NSPL partials per row; flag near-ties for np rescan
// ---------------------------------------------------------------------------
__global__ void k_combine(const float* __restrict__ pd1, const float* __restrict__ pd2,
                          const int* __restrict__ pi1, int* __restrict__ idxf,
                          int* __restrict__ rescan_cnt, int* __restrict__ rlist,
                          float* __restrict__ outIdx) {
  const int m = blockIdx.x * blockDim.x + threadIdx.x;
  if (m >= Mm) return;
  float a1 = INFINITY, a2 = INFINITY; int ai = 0x7fffffff;
  #pragma unroll
  for (int spl = 0; spl < NSPL; ++spl) {
    const size_t o = (size_t)spl * Mm + m;
    const float b1 = pd1[o], b2 = pd2[o]; const int bi = pi1[o];
    if (b1 < a1 || (b1 == a1 && bi < ai)) { a2 = fminf(a1, b2); a1 = b1; ai = bi; }
    else a2 = fminf(a2, b1);
  }
  idxf[m]   = ai;
  outIdx[m] = (float)ai;
  if (a2 - a1 <= RESCAN_MARGIN) { const int p = atomicAdd(rescan_cnt, 1); rlist[p] = m; }
}

// ---------------------------------------------------------------------------
// gather flagged rows into compact zg; compute np norms; init packed minima
// ---------------------------------------------------------------------------
__global__ void k_gather(const float* __restrict__ z, const int* __restrict__ rescan_cnt,
                         const int* __restrict__ rlist, float* __restrict__ zg,
                         float* __restrict__ Ag, unsigned long long* __restrict__ pbrow) {
  __shared__ float zr[Dd];
  const int cnt = min(*rescan_cnt, ZG_CAP);
  for (int it = blockIdx.x; it < cnt; it += gridDim.x) {
    const int m = rlist[it];
    const int b = m / Tt, t = m & (Tt - 1);
    __syncthreads();
    zr[threadIdx.x] = z[(size_t)b * Dd * Tt + (size_t)threadIdx.x * Tt + t];
    __syncthreads();
    zg[(size_t)it * Dd + threadIdx.x] = zr[threadIdx.x];
    if (threadIdx.x == 0) { Ag[it] = np_sumsq256(zr); pbrow[it] = ~0ull; }
  }
}

// ---------------------------------------------------------------------------
// chunked np-faithful rescan: block = (32-code chunk) x (row group).
// dq = fl32(fl32(A - 2*fl32(dot_f64)) + C_k); per-row argmin via packed
// (orderable-f32, idx) atomicMin -> exact first-index tie-break.
// ---------------------------------------------------------------------------
__global__ __launch_bounds__(256)
void k_rescan_part(const float* __restrict__ cb, const float* __restrict__ sc,
                   const int* __restrict__ rescan_cnt, const float* __restrict__ zg,
                   const float* __restrict__ Ag, unsigned long long* __restrict__ pbrow) {
  __shared__ float  cs[CHK * 257];
  __shared__ float  scs[CHK];
  __shared__ float  zf[Dd];
  __shared__ double pr[256];
  const int tid = threadIdx.x;
  const int cnt = min(*rescan_cnt, ZG_CAP);
  const int c = blockIdx.x >> 4;        // 256 chunks of 32 codes
  const int g = blockIdx.x & (GRP - 1);
  if (g >= cnt) return;
  const int k0 = c * CHK;
  for (int i = tid; i < CHK * Dd; i += 256) {
    const int code = i >> 8, d = i & 255;
    cs[code * 257 + d] = cb[(size_t)(k0 + code) * Dd + d];
  }
  if (tid < CHK) scs[tid] = sc[k0 + tid];
  const int code = tid & 31, seg = tid >> 5;
  __syncthreads();
  for (int it = g; it < cnt; it += GRP) {
    zf[tid] = zg[(size_t)it * Dd + tid];
    __syncthreads();
    const float* cp = &cs[code * 257 + seg * 32];
    const float* zp = &zf[seg * 32];
    double a0 = 0.0, a1 = 0.0, a2 = 0.0, a3 = 0.0;
    #pragma unroll
    for (int j = 0; j < 32; j += 4) {
      a0 = fma((double)cp[j+0], (double)zp[j+0], a0);
      a1 = fma((double)cp[j+1], (double)zp[j+1], a1);
      a2 = fma((double)cp[j+2], (double)zp[j+2], a2);
      a3 = fma((double)cp[j+3], (double)zp[j+3], a3);
    }
    pr[tid] = (a0 + a1) + (a2 + a3);
    __syncthreads();
    if (tid < CHK) {
      double M8 = 0.0;
      #pragma unroll
      for (int sg = 0; sg < 8; ++sg) M8 += pr[tid + sg * 32];
      const float M  = (float)M8;
      const float t1 = __fsub_rn(Ag[it], __fmul_rn(2.0f, M));
      const float dq = __fadd_rn(t1, scs[tid]);
      unsigned int fb = __float_as_uint(dq);
      fb = (fb & 0x80000000u) ? ~fb : (fb | 0x80000000u);   // orderable transform
      unsigned long long pack = ((unsigned long long)fb << 32) | (unsigned)(k0 + tid);
      #pragma unroll
      for (int off = 16; off; off >>= 1) {
        const unsigned long long o = __shfl_xor(pack, off);
        if (o < pack) pack = o;
      }
      if (tid == 0) atomicMin(pbrow + it, pack);
    }
    __syncthreads();
  }
}

// ---------------------------------------------------------------------------
// write back fast-rescanned indices
// ---------------------------------------------------------------------------
__global__ void k_rescan_final(const int* __restrict__ rescan_cnt, const int* __restrict__ rlist,
                               const unsigned long long* __restrict__ pbrow,
                               int* __restrict__ idxf, float* __restrict__ outIdx) {
  const int cnt = min(*rescan_cnt, ZG_CAP);
  const int it = blockIdx.x * blockDim.x + threadIdx.x;
  if (it < cnt) {
    const int idx = (int)(unsigned)(pbrow[it] & 0xFFFFFFFFull);
    const int m = rlist[it];
    idxf[m] = idx; outIdx[m] = (float)idx;
  }
}

// ---------------------------------------------------------------------------
// overflow fallback (it >= ZG_CAP): per-row full scan, normally 0 iterations
// ---------------------------------------------------------------------------
__global__ void k_rescan_slow(const float* __restrict__ z, const float* __restrict__ cb,
                              const float* __restrict__ sc,
                              const int* __restrict__ rescan_cnt, const int* __restrict__ rlist,
                              int* __restrict__ idxf, float* __restrict__ outIdx) {
  __shared__ float zrow[Dd];
  __shared__ float Ash;
  __shared__ float sval[256];
  __shared__ int   sidx[256];
  const int tid = threadIdx.x;
  const int cnt = *rescan_cnt;
  for (int it = ZG_CAP + blockIdx.x; it < cnt; it += gridDim.x) {
    const int m = rlist[it];
    const int b = m / Tt, t = m & (Tt - 1);
    __syncthreads();
    zrow[tid] = z[(size_t)b * Dd * Tt + (size_t)tid * Tt + t];
    __syncthreads();
    if (tid == 0) Ash = np_sumsq256(zrow);
    __syncthreads();
    const float A = Ash;
    float best = INFINITY; int bi = 0x7fffffff;
    for (int k = tid; k < Kk; k += 256) {
      const float* cr = cb + (size_t)k * Dd;
      double a0 = 0.0, a1 = 0.0, a2 = 0.0, a3 = 0.0;
      for (int d = 0; d < Dd; d += 4) {
        const float4 c4 = *(const float4*)(cr + d);
        a0 = fma((double)c4.x, (double)zrow[d+0], a0);
        a1 = fma((double)c4.y, (double)zrow[d+1], a1);
        a2 = fma((double)c4.z, (double)zrow[d+2], a2);
        a3 = fma((double)c4.w, (double)zrow[d+3], a3);
      }
      const float M  = (float)((a0 + a1) + (a2 + a3));
      const float t1 = __fsub_rn(A, __fmul_rn(2.0f, M));
      const float dq = __fadd_rn(t1, sc[k]);
      if (dq < best) { best = dq; bi = k; }
    }
    sval[tid] = best; sidx[tid] = bi;
    __syncthreads();
    for (int off = 128; off; off >>= 1) {
      if (tid < off) {
        if (sval[tid+off] < sval[tid] ||
            (sval[tid+off] == sval[tid] && sidx[tid+off] < sidx[tid])) {
          sval[tid] = sval[tid+off]; sidx[tid] = sidx[tid+off];
        }
      }
      __syncthreads();
    }
    if (tid == 0) { idxf[m] = sidx[0]; outIdx[m] = (float)sidx[0]; }
    __syncthreads();
  }
}

// ---------------------------------------------------------------------------
// gather z_q, write z_q_st, accumulate loss sum
// ---------------------------------------------------------------------------
__global__ void k_epilogue(const float* __restrict__ z, const float* __restrict__ cb,
                           const int* __restrict__ idxf, float* __restrict__ outZ,
                           double* __restrict__ loss_accum) {
  const int g  = blockIdx.x * blockDim.x + threadIdx.x;
  const int e4 = g * 4;
  const int t4 = e4 & (Tt - 1);
  const int bd = e4 >> 11;
  const int d  = bd & (Dd - 1);
  const int b  = bd >> 8;
  const float4 zv = *(const float4*)(z + e4);
  const int mb = b * Tt + t4;
  const float q0 = cb[(size_t)idxf[mb+0] * Dd + d];
  const float q1 = cb[(size_t)idxf[mb+1] * Dd + d];
  const float q2 = cb[(size_t)idxf[mb+2] * Dd + d];
  const float q3 = cb[(size_t)idxf[mb+3] * Dd + d];
  const float r0 = q0 - zv.x, r1 = q1 - zv.y, r2 = q2 - zv.z, r3 = q3 - zv.w;
  float4 o;
  o.x = zv.x + r0; o.y = zv.y + r1; o.z = zv.z + r2; o.w = zv.w + r3;
  *(float4*)(outZ + e4) = o;
  double ls = (double)r0*r0 + (double)r1*r1 + (double)r2*r2 + (double)r3*r3;
  #pragma unroll
  for (int off = 32; off; off >>= 1) ls += __shfl_down(ls, off);
  if ((threadIdx.x & 63) == 0) atomicAdd(loss_accum, ls);
}

__global__ void k_finalize(const double* __restrict__ loss_accum, float* __restrict__ outLoss) {
  const double mean = *loss_accum / (double)((size_t)Bz * Dd * Tt);
  *outLoss = (float)(mean + 0.1 * mean);
}

// ---------------------------------------------------------------------------
extern "C" void kernel_launch(void* const* d_in, const int* in_sizes, int n_in,
                              void* d_out, int out_size, void* d_ws, size_t ws_size,
                              hipStream_t stream) {
  (void)in_sizes; (void)n_in; (void)out_size; (void)ws_size;
  const float* z  = (const float*)d_in[0];   // (B, D, T) fp32
  const float* cb = (const float*)d_in[1];   // (K, D)    fp32

  float* outZ    = (float*)d_out;
  float* outIdx  = outZ + (size_t)Bz * Dd * Tt;
  float* outLoss = outIdx + Mm;

  char* w = (char*)d_ws;
  double*    loss_accum = (double*)w;    w += 16;
  int*       rescan_cnt = (int*)w;       w += 16;
  int*       rlist      = (int*)w;       w += sizeof(int)   * Mm;
  int*       idxf       = (int*)w;       w += sizeof(int)   * Mm;
  float*     sc         = (float*)w;     w += sizeof(float) * Kk;
  _Float16*  Ah         = (_Float16*)w;  w += sizeof(_Float16) * (size_t)Mm * Dd;
  _Float16*  Bh         = (_Float16*)w;  w += sizeof(_Float16) * (size_t)Kk * Dd;
  float*     zg         = (float*)w;     w += sizeof(float) * (size_t)ZG_CAP * Dd;
  float*     Ag         = (float*)w;     w += sizeof(float) * ZG_CAP;
  unsigned long long* pbrow = (unsigned long long*)w; w += sizeof(unsigned long long) * ZG_CAP;
  float*     pd1        = (float*)w;     w += sizeof(float) * (size_t)NSPL * Mm;
  float*     pd2        = (float*)w;     w += sizeof(float) * (size_t)NSPL * Mm;
  int*       pi1        = (int*)w;       /* total ~22.5 MB */

  k_cast_z      <<<dim3(1024), 256, 0, stream>>>(z, Ah);
  k_cast_cb     <<<dim3((Kk * Dd / 8) / 256), 256, 0, stream>>>(cb, Bh);
  k_prep        <<<dim3(Kk / 256), 256, 0, stream>>>(cb, sc, loss_accum, rescan_cnt);
  k_mfma        <<<dim3((Mm / 128) * NSPL), 512, 0, stream>>>(Ah, Bh, sc, pd1, pd2, pi1);
  k_combine     <<<dim3(Mm / 256), 256, 0, stream>>>(pd1, pd2, pi1, idxf, rescan_cnt, rlist, outIdx);
  k_gather      <<<dim3(256), 256, 0, stream>>>(z, rescan_cnt, rlist, zg, Ag, pbrow);
  k_rescan_part <<<dim3((Kk / CHK) * GRP), 256, 0, stream>>>(cb, sc, rescan_cnt, zg, Ag, pbrow);
  k_rescan_slow <<<dim3(64), 256, 0, stream>>>(z, cb, sc, rescan_cnt, rlist, idxf, outIdx);
  k_rescan_final<<<dim3(ZG_CAP / 256), 256, 0, stream>>>(rescan_cnt, rlist, pbrow, idxf, outIdx);
  k_epilogue    <<<dim3(((size_t)Mm * Dd / 4) / 256), 256, 0, stream>>>(z, cb, idxf, outZ, loss_accum);
  k_finalize    <<<dim3(1), 1, 0, stream>>>(loss_accum, outLoss);
}

// Round 5
// 769.144 us; speedup vs baseline: 2.1763x; 1.1899x over previous
//
#include <hip/hip_runtime.h>
#include <hip/hip_bf16.h>
#include <float.h>
#include <math.h>

#define Bz 8
#define Dd 256
#define Tt 2048
#define Kk 8192
#define Mm (Bz*Tt)          // 16384 rows (b*T + t)

// Scorer tiling: block = 64 rows x 1024 codes, 256 threads, 4 waves (2m x 2n)
#define NSPL 8
#define BS_STRIDE 72        // f16 units; 144 B row stride

// Rescan chunking
#define CHK 32
#define GRP 16
#define ZG_CAP 8192

// Margin: covers f16 fast-pass score error + np fp32 quantization straddle
#define RESCAN_MARGIN 6e-4f

typedef __attribute__((ext_vector_type(8))) _Float16 f16x8;
typedef __attribute__((ext_vector_type(4))) float    f32x4;

// ---------------------------------------------------------------------------
// numpy-faithful pairwise sum of squares (blocksize-128 pairwise, 8 accums)
// ---------------------------------------------------------------------------
__device__ __forceinline__ float np_sumsq128(const float* __restrict__ x) {
  float r0 = __fmul_rn(x[0], x[0]);
  float r1 = __fmul_rn(x[1], x[1]);
  float r2 = __fmul_rn(x[2], x[2]);
  float r3 = __fmul_rn(x[3], x[3]);
  float r4 = __fmul_rn(x[4], x[4]);
  float r5 = __fmul_rn(x[5], x[5]);
  float r6 = __fmul_rn(x[6], x[6]);
  float r7 = __fmul_rn(x[7], x[7]);
  for (int i = 8; i < 128; i += 8) {
    r0 = __fadd_rn(r0, __fmul_rn(x[i+0], x[i+0]));
    r1 = __fadd_rn(r1, __fmul_rn(x[i+1], x[i+1]));
    r2 = __fadd_rn(r2, __fmul_rn(x[i+2], x[i+2]));
    r3 = __fadd_rn(r3, __fmul_rn(x[i+3], x[i+3]));
    r4 = __fadd_rn(r4, __fmul_rn(x[i+4], x[i+4]));
    r5 = __fadd_rn(r5, __fmul_rn(x[i+5], x[i+5]));
    r6 = __fadd_rn(r6, __fmul_rn(x[i+6], x[i+6]));
    r7 = __fadd_rn(r7, __fmul_rn(x[i+7], x[i+7]));
  }
  return __fadd_rn(__fadd_rn(__fadd_rn(r0, r1), __fadd_rn(r2, r3)),
                   __fadd_rn(__fadd_rn(r4, r5), __fadd_rn(r6, r7)));
}
__device__ __forceinline__ float np_sumsq256(const float* __restrict__ x) {
  return __fadd_rn(np_sumsq128(x), np_sumsq128(x + 128));
}

// ---------------------------------------------------------------------------
// transpose-cast z (B,D,T) f32 -> Ah (M, D) f16
// ---------------------------------------------------------------------------
__global__ void k_cast_z(const float* __restrict__ z, _Float16* __restrict__ Ah) {
  __shared__ _Float16 tile[64][64 + 8];
  const int tid = threadIdx.x;
  const int bidx = blockIdx.x;            // 8 * 4 * 32 = 1024
  const int b  = bidx >> 7;
  const int dt = (bidx >> 5) & 3;
  const int tt = bidx & 31;
  const int d0 = dt * 64, t0 = tt * 64;
  const float* zb = z + ((size_t)b * Dd + d0) * Tt + t0;
  #pragma unroll
  for (int p = 0; p < 4; ++p) {
    const int d  = p * 16 + (tid >> 4);
    const int tl = (tid & 15) * 4;
    const float4 v = *(const float4*)(zb + (size_t)d * Tt + tl);
    tile[tl+0][d] = (_Float16)v.x;
    tile[tl+1][d] = (_Float16)v.y;
    tile[tl+2][d] = (_Float16)v.z;
    tile[tl+3][d] = (_Float16)v.w;
  }
  __syncthreads();
  const int r = tid >> 2, seg = tid & 3;
  const int m = b * Tt + t0 + r;
  int4* dst = (int4*)(Ah + (size_t)m * Dd + d0 + seg * 16);
  const int4* srcv = (const int4*)(&tile[r][seg * 16]);
  dst[0] = srcv[0];
  dst[1] = srcv[1];
}

// ---------------------------------------------------------------------------
// cast codebook f32 -> f16, prescaled by 256 (avoids f16 subnormals)
// ---------------------------------------------------------------------------
__global__ void k_cast_cb(const float* __restrict__ cb, _Float16* __restrict__ Bh) {
  const size_t g = (size_t)blockIdx.x * blockDim.x + threadIdx.x;
  const float4 v0 = *(const float4*)(cb + g * 8);
  const float4 v1 = *(const float4*)(cb + g * 8 + 4);
  f16x8 o;
  o[0] = (_Float16)(v0.x * 256.f); o[1] = (_Float16)(v0.y * 256.f);
  o[2] = (_Float16)(v0.z * 256.f); o[3] = (_Float16)(v0.w * 256.f);
  o[4] = (_Float16)(v1.x * 256.f); o[5] = (_Float16)(v1.y * 256.f);
  o[6] = (_Float16)(v1.z * 256.f); o[7] = (_Float16)(v1.w * 256.f);
  *(f16x8*)(Bh + g * 8) = o;
}

// ---------------------------------------------------------------------------
// np-faithful codebook norms, wave-parallel: 8 lanes per row, each lane owns
// one of numpy's 8 accumulator chains; commutative fadd tree == np combine.
// ---------------------------------------------------------------------------
__global__ void k_prep(const float* __restrict__ cb, float* __restrict__ sc,
                       double* __restrict__ loss_accum, int* __restrict__ rescan_cnt) {
  const int gid = blockIdx.x * blockDim.x + threadIdx.x;
  if (gid == 0) { *loss_accum = 0.0; *rescan_cnt = 0; }
  const int lane = gid & 63;
  const int j = lane & 7, sub = lane >> 3;
  const int row = (gid >> 6) * 8 + sub;
  if (row >= Kk) return;
  const float* x = cb + (size_t)row * Dd;
  float c0 = __fmul_rn(x[j], x[j]);
  float c1 = __fmul_rn(x[128 + j], x[128 + j]);
  #pragma unroll
  for (int i = 8; i < 128; i += 8) {
    c0 = __fadd_rn(c0, __fmul_rn(x[j + i], x[j + i]));
    c1 = __fadd_rn(c1, __fmul_rn(x[128 + j + i], x[128 + j + i]));
  }
  #pragma unroll
  for (int off = 1; off <= 4; off <<= 1) {
    c0 = __fadd_rn(c0, __shfl_xor(c0, off));
    c1 = __fadd_rn(c1, __shfl_xor(c1, off));
  }
  if (j == 0) sc[row] = __fadd_rn(c0, c1);
}

// ---------------------------------------------------------------------------
// f16 MFMA score pass v4: A register-resident with STATIC indexing
// (kc fully unrolled), B LDS double-buffer, fused per-row top-2.
// Block: 64 rows x 1024 codes; 4 waves in 2(m) x 2(n); wave-tile 32x64.
// ---------------------------------------------------------------------------
__global__ __launch_bounds__(256, 3)
void k_mfma(const _Float16* __restrict__ Ah, const _Float16* __restrict__ Bh,
            const float* __restrict__ sc,
            float* __restrict__ pd1, float* __restrict__ pd2, int* __restrict__ pi1) {
  __shared__ __align__(16) _Float16 Bs[2][128 * BS_STRIDE];   // 36,864 B

  const int tid  = threadIdx.x;
  const int bx   = blockIdx.x & (NSPL - 1);
  const int by   = blockIdx.x >> 3;
  const int m0   = by * 64, n0 = bx * 1024;
  const int w    = tid >> 6, lane = tid & 63;
  const int wy   = w >> 1, wx = w & 1;
  const int l15  = lane & 15, quad = lane >> 4;

  // ---- A fragments, full K, statically indexed (kc/ks/mi all unrolled)
  f16x8 af[4][2][2];
  {
    const _Float16* Abase = Ah + (size_t)(m0 + wy * 32 + l15) * Dd + quad * 8;
    #pragma unroll
    for (int kc = 0; kc < 4; ++kc)
      #pragma unroll
      for (int ks = 0; ks < 2; ++ks)
        #pragma unroll
        for (int mi = 0; mi < 2; ++mi)
          af[kc][ks][mi] = *(const f16x8*)(Abase + (size_t)mi * 16 * Dd + kc * 64 + ks * 32);
  }

  // ---- B staging: 2 threads/row, 32 f16 (64 B) each
  const int srow = tid >> 1, sseg = tid & 1;
  const _Float16* gB = Bh + (size_t)(n0 + srow) * Dd + sseg * 32;
  _Float16* wB0 = &Bs[0][0] + srow * BS_STRIDE + sseg * 32;

  int4 rb[4];
  #define LOADB(sidx) { \
    const _Float16* p = gB + (size_t)((sidx) >> 2) * (128 * Dd) + ((sidx) & 3) * 64; \
    rb[0] = ((const int4*)p)[0]; rb[1] = ((const int4*)p)[1]; \
    rb[2] = ((const int4*)p)[2]; rb[3] = ((const int4*)p)[3]; }

  LOADB(0);

  f32x4 acc[2][4];
  #pragma unroll
  for (int mi = 0; mi < 2; ++mi)
    #pragma unroll
    for (int ni = 0; ni < 4; ++ni)
      acc[mi][ni] = (f32x4){0.f, 0.f, 0.f, 0.f};

  float s1[8], s2[8]; int i1[8];
  #pragma unroll
  for (int q = 0; q < 8; ++q) { s1[q] = INFINITY; s2[q] = INFINITY; i1[q] = 0x7fffffff; }

  for (int nt = 0; nt < 8; ++nt) {
    float scv[4];
    #pragma unroll
    for (int ni = 0; ni < 4; ++ni)
      scv[ni] = sc[n0 + nt * 128 + wx * 64 + ni * 16 + l15];

    #pragma unroll
    for (int kc = 0; kc < 4; ++kc) {
      const int s = nt * 4 + kc;
      const int buf = kc & 1;                 // compile-time within unroll
      __syncthreads();
      {
        _Float16* d = wB0 + buf * (128 * BS_STRIDE);
        *(int4*)(d)      = rb[0];
        *(int4*)(d + 8)  = rb[1];
        *(int4*)(d + 16) = rb[2];
        *(int4*)(d + 24) = rb[3];
      }
      __syncthreads();
      if (s < 31) { LOADB(s + 1); }
      #pragma unroll
      for (int ks = 0; ks < 2; ++ks) {
        f16x8 bf[4];
        #pragma unroll
        for (int ni = 0; ni < 4; ++ni)
          bf[ni] = *(const f16x8*)(&Bs[buf][0] + (wx * 64 + ni * 16 + l15) * BS_STRIDE + ks * 32 + quad * 8);
        #pragma unroll
        for (int mi = 0; mi < 2; ++mi)
          #pragma unroll
          for (int ni = 0; ni < 4; ++ni)
            acc[mi][ni] = __builtin_amdgcn_mfma_f32_16x16x32_f16(af[kc][ks][mi], bf[ni], acc[mi][ni], 0, 0, 0);
      }
    }

    // fold this 128-col n-tile into per-thread top-2 (k ascending)
    #pragma unroll
    for (int mi = 0; mi < 2; ++mi)
      #pragma unroll
      for (int r = 0; r < 4; ++r) {
        const int q = mi * 4 + r;
        #pragma unroll
        for (int ni = 0; ni < 4; ++ni) {
          const float sv = fmaf(-0.0078125f, acc[mi][ni][r], scv[ni]);  // -2/256
          const int   k  = n0 + nt * 128 + wx * 64 + ni * 16 + l15;
          if (sv < s1[q]) { s2[q] = s1[q]; s1[q] = sv; i1[q] = k; }
          else if (sv < s2[q]) s2[q] = sv;
          acc[mi][ni][r] = 0.f;
        }
      }
  }

  // ---- merge across the 16 lanes (same rows, different cols)
  #pragma unroll
  for (int off = 1; off <= 8; off <<= 1)
    #pragma unroll
    for (int q = 0; q < 8; ++q) {
      const float o1 = __shfl_xor(s1[q], off);
      const float o2 = __shfl_xor(s2[q], off);
      const int   oi = __shfl_xor(i1[q], off);
      if (o1 < s1[q] || (o1 == s1[q] && oi < i1[q])) {
        s2[q] = fminf(s1[q], o2); s1[q] = o1; i1[q] = oi;
      } else s2[q] = fminf(s2[q], o1);
    }

  // ---- cross-wave (wx) merge through LDS
  __syncthreads();
  float* red1 = (float*)&Bs[0][0];
  float* red2 = red1 + 128;
  int*   redi = (int*)(red1 + 256);
  if (l15 == 0) {
    #pragma unroll
    for (int mi = 0; mi < 2; ++mi)
      #pragma unroll
      for (int r = 0; r < 4; ++r) {
        const int q  = mi * 4 + r;
        const int ml = wy * 32 + mi * 16 + quad * 4 + r;
        red1[ml * 2 + wx] = s1[q];
        red2[ml * 2 + wx] = s2[q];
        redi[ml * 2 + wx] = i1[q];
      }
  }
  __syncthreads();
  if (tid < 64) {
    float a1 = red1[tid * 2], a2 = red2[tid * 2]; int ai = redi[tid * 2];
    const float b1 = red1[tid * 2 + 1], b2 = red2[tid * 2 + 1];
    const int   bi = redi[tid * 2 + 1];
    if (b1 < a1 || (b1 == a1 && bi < ai)) { a2 = fminf(a1, b2); a1 = b1; ai = bi; }
    else a2 = fminf(a2, b1);
    const size_t o = (size_t)bx * Mm + (size_t)(m0 + tid);
    pd1[o] = a1; pd2[o] = a2; pi1[o] = ai;
  }
}

// ---------------------------------------------------------------------------
// combine the NSPL partials per row; flag near-ties for np rescan
// ---------------------------------------------------------------------------
__global__ void k_combine(const float* __restrict__ pd1, const float* __restrict__ pd2,
                          const int* __restrict__ pi1, int* __restrict__ idxf,
                          int* __restrict__ rescan_cnt, int* __restrict__ rlist,
                          float* __restrict__ outIdx) {
  const int m = blockIdx.x * blockDim.x + threadIdx.x;
  if (m >= Mm) return;
  float a1 = INFINITY, a2 = INFINITY; int ai = 0x7fffffff;
  #pragma unroll
  for (int spl = 0; spl < NSPL; ++spl) {
    const size_t o = (size_t)spl * Mm + m;
    const float b1 = pd1[o], b2 = pd2[o]; const int bi = pi1[o];
    if (b1 < a1 || (b1 == a1 && bi < ai)) { a2 = fminf(a1, b2); a1 = b1; ai = bi; }
    else a2 = fminf(a2, b1);
  }
  idxf[m]   = ai;
  outIdx[m] = (float)ai;
  if (a2 - a1 <= RESCAN_MARGIN) { const int p = atomicAdd(rescan_cnt, 1); rlist[p] = m; }
}

// ---------------------------------------------------------------------------
// gather flagged rows into compact zg; np norms; init packed minima
// ---------------------------------------------------------------------------
__global__ void k_gather(const float* __restrict__ z, const int* __restrict__ rescan_cnt,
                         const int* __restrict__ rlist, float* __restrict__ zg,
                         float* __restrict__ Ag, unsigned long long* __restrict__ pbrow) {
  __shared__ float zr[Dd];
  const int cnt = min(*rescan_cnt, ZG_CAP);
  for (int it = blockIdx.x; it < cnt; it += gridDim.x) {
    const int m = rlist[it];
    const int b = m / Tt, t = m & (Tt - 1);
    __syncthreads();
    zr[threadIdx.x] = z[(size_t)b * Dd * Tt + (size_t)threadIdx.x * Tt + t];
    __syncthreads();
    zg[(size_t)it * Dd + threadIdx.x] = zr[threadIdx.x];
    if (threadIdx.x == 0) { Ag[it] = np_sumsq256(zr); pbrow[it] = ~0ull; }
  }
}

// ---------------------------------------------------------------------------
// chunked np-faithful rescan
// ---------------------------------------------------------------------------
__global__ __launch_bounds__(256)
void k_rescan_part(const float* __restrict__ cb, const float* __restrict__ sc,
                   const int* __restrict__ rescan_cnt, const float* __restrict__ zg,
                   const float* __restrict__ Ag, unsigned long long* __restrict__ pbrow) {
  __shared__ float  cs[CHK * 257];
  __shared__ float  scs[CHK];
  __shared__ float  zf[Dd];
  __shared__ double pr[256];
  const int tid = threadIdx.x;
  const int cnt = min(*rescan_cnt, ZG_CAP);
  const int c = blockIdx.x >> 4;
  const int g = blockIdx.x & (GRP - 1);
  if (g >= cnt) return;
  const int k0 = c * CHK;
  for (int i = tid; i < CHK * Dd; i += 256) {
    const int code = i >> 8, d = i & 255;
    cs[code * 257 + d] = cb[(size_t)(k0 + code) * Dd + d];
  }
  if (tid < CHK) scs[tid] = sc[k0 + tid];
  const int code = tid & 31, seg = tid >> 5;
  __syncthreads();
  for (int it = g; it < cnt; it += GRP) {
    zf[tid] = zg[(size_t)it * Dd + tid];
    __syncthreads();
    const float* cp = &cs[code * 257 + seg * 32];
    const float* zp = &zf[seg * 32];
    double a0 = 0.0, a1 = 0.0, a2 = 0.0, a3 = 0.0;
    #pragma unroll
    for (int j = 0; j < 32; j += 4) {
      a0 = fma((double)cp[j+0], (double)zp[j+0], a0);
      a1 = fma((double)cp[j+1], (double)zp[j+1], a1);
      a2 = fma((double)cp[j+2], (double)zp[j+2], a2);
      a3 = fma((double)cp[j+3], (double)zp[j+3], a3);
    }
    pr[tid] = (a0 + a1) + (a2 + a3);
    __syncthreads();
    if (tid < CHK) {
      double M8 = 0.0;
      #pragma unroll
      for (int sg = 0; sg < 8; ++sg) M8 += pr[tid + sg * 32];
      const float M  = (float)M8;
      const float t1 = __fsub_rn(Ag[it], __fmul_rn(2.0f, M));
      const float dq = __fadd_rn(t1, scs[tid]);
      unsigned int fb = __float_as_uint(dq);
      fb = (fb & 0x80000000u) ? ~fb : (fb | 0x80000000u);
      unsigned long long pack = ((unsigned long long)fb << 32) | (unsigned)(k0 + tid);
      #pragma unroll
      for (int off = 16; off; off >>= 1) {
        const unsigned long long o = __shfl_xor(pack, off);
        if (o < pack) pack = o;
      }
      if (tid == 0) atomicMin(pbrow + it, pack);
    }
    __syncthreads();
  }
}

__global__ void k_rescan_final(const int* __restrict__ rescan_cnt, const int* __restrict__ rlist,
                               const unsigned long long* __restrict__ pbrow,
                               int* __restrict__ idxf, float* __restrict__ outIdx) {
  const int cnt = min(*rescan_cnt, ZG_CAP);
  const int it = blockIdx.x * blockDim.x + threadIdx.x;
  if (it < cnt) {
    const int idx = (int)(unsigned)(pbrow[it] & 0xFFFFFFFFull);
    const int m = rlist[it];
    idxf[m] = idx; outIdx[m] = (float)idx;
  }
}

// overflow fallback: normally 0 iterations
__global__ void k_rescan_slow(const float* __restrict__ z, const float* __restrict__ cb,
                              const float* __restrict__ sc,
                              const int* __restrict__ rescan_cnt, const int* __restrict__ rlist,
                              int* __restrict__ idxf, float* __restrict__ outIdx) {
  __shared__ float zrow[Dd];
  __shared__ float Ash;
  __shared__ float sval[256];
  __shared__ int   sidx[256];
  const int tid = threadIdx.x;
  const int cnt = *rescan_cnt;
  for (int it = ZG_CAP + blockIdx.x; it < cnt; it += gridDim.x) {
    const int m = rlist[it];
    const int b = m / Tt, t = m & (Tt - 1);
    __syncthreads();
    zrow[tid] = z[(size_t)b * Dd * Tt + (size_t)tid * Tt + t];
    __syncthreads();
    if (tid == 0) Ash = np_sumsq256(zrow);
    __syncthreads();
    const float A = Ash;
    float best = INFINITY; int bi = 0x7fffffff;
    for (int k = tid; k < Kk; k += 256) {
      const float* cr = cb + (size_t)k * Dd;
      double a0 = 0.0, a1 = 0.0, a2 = 0.0, a3 = 0.0;
      for (int d = 0; d < Dd; d += 4) {
        const float4 c4 = *(const float4*)(cr + d);
        a0 = fma((double)c4.x, (double)zrow[d+0], a0);
        a1 = fma((double)c4.y, (double)zrow[d+1], a1);
        a2 = fma((double)c4.z, (double)zrow[d+2], a2);
        a3 = fma((double)c4.w, (double)zrow[d+3], a3);
      }
      const float M  = (float)((a0 + a1) + (a2 + a3));
      const float t1 = __fsub_rn(A, __fmul_rn(2.0f, M));
      const float dq = __fadd_rn(t1, sc[k]);
      if (dq < best) { best = dq; bi = k; }
    }
    sval[tid] = best; sidx[tid] = bi;
    __syncthreads();
    for (int off = 128; off; off >>= 1) {
      if (tid < off) {
        if (sval[tid+off] < sval[tid] ||
            (sval[tid+off] == sval[tid] && sidx[tid+off] < sidx[tid])) {
          sval[tid] = sval[tid+off]; sidx[tid] = sidx[tid+off];
        }
      }
      __syncthreads();
    }
    if (tid == 0) { idxf[m] = sidx[0]; outIdx[m] = (float)sidx[0]; }
    __syncthreads();
  }
}

// ---------------------------------------------------------------------------
// gather z_q rows coalesced: zq[m][d] = cb[idxf[m]][d]
// ---------------------------------------------------------------------------
__global__ void k_gather_q(const float* __restrict__ cb, const int* __restrict__ idxf,
                           float* __restrict__ zq) {
  const int g = blockIdx.x * blockDim.x + threadIdx.x;
  const int m = g >> 6;
  const int d4 = (g & 63) * 4;
  const int idx = idxf[m];
  const float4 q = *(const float4*)(cb + (size_t)idx * Dd + d4);
  *(float4*)(zq + (size_t)m * Dd + d4) = q;
}

// ---------------------------------------------------------------------------
// transpose zq (M,D) -> out (B,D,T) with STE formula + loss accumulation
// ---------------------------------------------------------------------------
__global__ void k_out(const float* __restrict__ z, const float* __restrict__ zq,
                      float* __restrict__ outZ, double* __restrict__ loss_accum) {
  __shared__ float tile[64][65];          // [d][t]
  const int tid = threadIdx.x;
  const int bidx = blockIdx.x;            // 8 * 4 * 32 = 1024
  const int b  = bidx >> 7;
  const int dt = (bidx >> 5) & 3;
  const int tt = bidx & 31;
  const int d0 = dt * 64, t0 = tt * 64;
  // phase 1: read zq rows coalesced
  {
    const int r = tid >> 2, seg = tid & 3;
    const float* src = zq + (size_t)(b * Tt + t0 + r) * Dd + d0 + seg * 16;
    #pragma unroll
    for (int q4 = 0; q4 < 4; ++q4) {
      const float4 v = *(const float4*)(src + q4 * 4);
      tile[seg * 16 + q4 * 4 + 0][r] = v.x;
      tile[seg * 16 + q4 * 4 + 1][r] = v.y;
      tile[seg * 16 + q4 * 4 + 2][r] = v.z;
      tile[seg * 16 + q4 * 4 + 3][r] = v.w;
    }
  }
  __syncthreads();
  // phase 2: write out along t, fuse STE + loss
  const float* zbase = z + ((size_t)b * Dd + d0) * Tt + t0;
  float*       obase = outZ + ((size_t)b * Dd + d0) * Tt + t0;
  double ls = 0.0;
  #pragma unroll
  for (int p = 0; p < 4; ++p) {
    const int d  = p * 16 + (tid >> 4);
    const int t4 = (tid & 15) * 4;
    const float4 zv = *(const float4*)(zbase + (size_t)d * Tt + t4);
    const float q0 = tile[d][t4+0], q1 = tile[d][t4+1];
    const float q2 = tile[d][t4+2], q3 = tile[d][t4+3];
    const float r0 = q0 - zv.x, r1 = q1 - zv.y, r2 = q2 - zv.z, r3 = q3 - zv.w;
    float4 o;
    o.x = zv.x + r0; o.y = zv.y + r1; o.z = zv.z + r2; o.w = zv.w + r3;
    *(float4*)(obase + (size_t)d * Tt + t4) = o;
    ls += (double)r0*r0 + (double)r1*r1 + (double)r2*r2 + (double)r3*r3;
  }
  #pragma unroll
  for (int off = 32; off; off >>= 1) ls += __shfl_down(ls, off);
  if ((tid & 63) == 0) atomicAdd(loss_accum, ls);
}

__global__ void k_finalize(const double* __restrict__ loss_accum, float* __restrict__ outLoss) {
  const double mean = *loss_accum / (double)((size_t)Bz * Dd * Tt);
  *outLoss = (float)(mean + 0.1 * mean);
}

// ---------------------------------------------------------------------------
extern "C" void kernel_launch(void* const* d_in, const int* in_sizes, int n_in,
                              void* d_out, int out_size, void* d_ws, size_t ws_size,
                              hipStream_t stream) {
  (void)in_sizes; (void)n_in; (void)out_size; (void)ws_size;
  const float* z  = (const float*)d_in[0];   // (B, D, T) fp32
  const float* cb = (const float*)d_in[1];   // (K, D)    fp32

  float* outZ    = (float*)d_out;
  float* outIdx  = outZ + (size_t)Bz * Dd * Tt;
  float* outLoss = outIdx + Mm;

  char* w = (char*)d_ws;
  double*    loss_accum = (double*)w;    w += 16;
  int*       rescan_cnt = (int*)w;       w += 16;
  int*       rlist      = (int*)w;       w += sizeof(int)   * Mm;
  int*       idxf       = (int*)w;       w += sizeof(int)   * Mm;
  float*     sc         = (float*)w;     w += sizeof(float) * Kk;
  _Float16*  Ah         = (_Float16*)w;  w += sizeof(_Float16) * (size_t)Mm * Dd;
  _Float16*  Bh         = (_Float16*)w;  w += sizeof(_Float16) * (size_t)Kk * Dd;
  float*     zg         = (float*)w;     w += sizeof(float) * (size_t)ZG_CAP * Dd;
  float*     Ag         = (float*)w;     w += sizeof(float) * ZG_CAP;
  unsigned long long* pbrow = (unsigned long long*)w; w += sizeof(unsigned long long) * ZG_CAP;
  float*     pd1        = (float*)w;     w += sizeof(float) * (size_t)NSPL * Mm;
  float*     pd2        = (float*)w;     w += sizeof(float) * (size_t)NSPL * Mm;
  int*       pi1        = (int*)w;       /* total ~23 MB */

  // zq (16.8 MB) overlays Ah+Bh+zg (21 MB) — all dead before k_gather_q runs
  float*     zq         = (float*)Ah;

  k_cast_z      <<<dim3(1024), 256, 0, stream>>>(z, Ah);
  k_cast_cb     <<<dim3((Kk * Dd / 8) / 256), 256, 0, stream>>>(cb, Bh);
  k_prep        <<<dim3(Kk * 8 / 256), 256, 0, stream>>>(cb, sc, loss_accum, rescan_cnt);
  k_mfma        <<<dim3((Mm / 64) * NSPL), 256, 0, stream>>>(Ah, Bh, sc, pd1, pd2, pi1);
  k_combine     <<<dim3(Mm / 256), 256, 0, stream>>>(pd1, pd2, pi1, idxf, rescan_cnt, rlist, outIdx);
  k_gather      <<<dim3(256), 256, 0, stream>>>(z, rescan_cnt, rlist, zg, Ag, pbrow);
  k_rescan_part <<<dim3((Kk / CHK) * GRP), 256, 0, stream>>>(cb, sc, rescan_cnt, zg, Ag, pbrow);
  k_rescan_slow <<<dim3(64), 256, 0, stream>>>(z, cb, sc, rescan_cnt, rlist, idxf, outIdx);
  k_rescan_final<<<dim3(ZG_CAP / 256), 256, 0, stream>>>(rescan_cnt, rlist, pbrow, idxf, outIdx);
  k_gather_q    <<<dim3((size_t)Mm * 64 / 256), 256, 0, stream>>>(cb, idxf, zq);
  k_out         <<<dim3(1024), 256, 0, stream>>>(z, zq, outZ, loss_accum);
  k_finalize    <<<dim3(1), 1, 0, stream>>>(loss_accum, outLoss);
}

// Round 6
// 676.274 us; speedup vs baseline: 2.4752x; 1.1373x over previous
//
#include <hip/hip_runtime.h>
#include <hip/hip_bf16.h>
#include <float.h>
#include <math.h>

#define Bz 8
#define Dd 256
#define Tt 2048
#define Kk 8192
#define Mm (Bz*Tt)          // 16384 rows (b*T + t)

// Scorer: block = 128 rows x 128 codes, 4 waves (2m x 2n), wave-tile 64x64.
// No LDS in the K-loop: A/B fragments read straight from L2-resident Ah/Bh.
#define NSPL 64             // 8192/128 column splits

// Rescan chunking
#define CHK 32
#define GRP 16
#define ZG_CAP 4096

// Margin: covers f16 fast-pass score error + np fp32 quantization straddle
#define RESCAN_MARGIN 6e-4f

typedef __attribute__((ext_vector_type(8))) _Float16 f16x8;
typedef __attribute__((ext_vector_type(4))) float    f32x4;

// ---------------------------------------------------------------------------
// numpy-faithful pairwise sum of squares (blocksize-128 pairwise, 8 accums)
// ---------------------------------------------------------------------------
__device__ __forceinline__ float np_sumsq128(const float* __restrict__ x) {
  float r0 = __fmul_rn(x[0], x[0]);
  float r1 = __fmul_rn(x[1], x[1]);
  float r2 = __fmul_rn(x[2], x[2]);
  float r3 = __fmul_rn(x[3], x[3]);
  float r4 = __fmul_rn(x[4], x[4]);
  float r5 = __fmul_rn(x[5], x[5]);
  float r6 = __fmul_rn(x[6], x[6]);
  float r7 = __fmul_rn(x[7], x[7]);
  for (int i = 8; i < 128; i += 8) {
    r0 = __fadd_rn(r0, __fmul_rn(x[i+0], x[i+0]));
    r1 = __fadd_rn(r1, __fmul_rn(x[i+1], x[i+1]));
    r2 = __fadd_rn(r2, __fmul_rn(x[i+2], x[i+2]));
    r3 = __fadd_rn(r3, __fmul_rn(x[i+3], x[i+3]));
    r4 = __fadd_rn(r4, __fmul_rn(x[i+4], x[i+4]));
    r5 = __fadd_rn(r5, __fmul_rn(x[i+5], x[i+5]));
    r6 = __fadd_rn(r6, __fmul_rn(x[i+6], x[i+6]));
    r7 = __fadd_rn(r7, __fmul_rn(x[i+7], x[i+7]));
  }
  return __fadd_rn(__fadd_rn(__fadd_rn(r0, r1), __fadd_rn(r2, r3)),
                   __fadd_rn(__fadd_rn(r4, r5), __fadd_rn(r6, r7)));
}
__device__ __forceinline__ float np_sumsq256(const float* __restrict__ x) {
  return __fadd_rn(np_sumsq128(x), np_sumsq128(x + 128));
}

// ---------------------------------------------------------------------------
// transpose-cast z (B,D,T) f32 -> Ah (M, D) f16
// ---------------------------------------------------------------------------
__global__ void k_cast_z(const float* __restrict__ z, _Float16* __restrict__ Ah) {
  __shared__ _Float16 tile[64][64 + 8];
  const int tid = threadIdx.x;
  const int bidx = blockIdx.x;            // 8 * 4 * 32 = 1024
  const int b  = bidx >> 7;
  const int dt = (bidx >> 5) & 3;
  const int tt = bidx & 31;
  const int d0 = dt * 64, t0 = tt * 64;
  const float* zb = z + ((size_t)b * Dd + d0) * Tt + t0;
  #pragma unroll
  for (int p = 0; p < 4; ++p) {
    const int d  = p * 16 + (tid >> 4);
    const int tl = (tid & 15) * 4;
    const float4 v = *(const float4*)(zb + (size_t)d * Tt + tl);
    tile[tl+0][d] = (_Float16)v.x;
    tile[tl+1][d] = (_Float16)v.y;
    tile[tl+2][d] = (_Float16)v.z;
    tile[tl+3][d] = (_Float16)v.w;
  }
  __syncthreads();
  const int r = tid >> 2, seg = tid & 3;
  const int m = b * Tt + t0 + r;
  int4* dst = (int4*)(Ah + (size_t)m * Dd + d0 + seg * 16);
  const int4* srcv = (const int4*)(&tile[r][seg * 16]);
  dst[0] = srcv[0];
  dst[1] = srcv[1];
}

// ---------------------------------------------------------------------------
// cast codebook f32 -> f16, prescaled by 256 (avoids f16 subnormals)
// ---------------------------------------------------------------------------
__global__ void k_cast_cb(const float* __restrict__ cb, _Float16* __restrict__ Bh) {
  const size_t g = (size_t)blockIdx.x * blockDim.x + threadIdx.x;
  const float4 v0 = *(const float4*)(cb + g * 8);
  const float4 v1 = *(const float4*)(cb + g * 8 + 4);
  f16x8 o;
  o[0] = (_Float16)(v0.x * 256.f); o[1] = (_Float16)(v0.y * 256.f);
  o[2] = (_Float16)(v0.z * 256.f); o[3] = (_Float16)(v0.w * 256.f);
  o[4] = (_Float16)(v1.x * 256.f); o[5] = (_Float16)(v1.y * 256.f);
  o[6] = (_Float16)(v1.z * 256.f); o[7] = (_Float16)(v1.w * 256.f);
  *(f16x8*)(Bh + g * 8) = o;
}

// ---------------------------------------------------------------------------
// np-faithful codebook norms, wave-parallel (8 lanes own np's 8 acc chains)
// ---------------------------------------------------------------------------
__global__ void k_prep(const float* __restrict__ cb, float* __restrict__ sc,
                       double* __restrict__ loss_accum, int* __restrict__ rescan_cnt) {
  const int gid = blockIdx.x * blockDim.x + threadIdx.x;
  if (gid == 0) { *loss_accum = 0.0; *rescan_cnt = 0; }
  const int lane = gid & 63;
  const int j = lane & 7, sub = lane >> 3;
  const int row = (gid >> 6) * 8 + sub;
  if (row >= Kk) return;
  const float* x = cb + (size_t)row * Dd;
  float c0 = __fmul_rn(x[j], x[j]);
  float c1 = __fmul_rn(x[128 + j], x[128 + j]);
  #pragma unroll
  for (int i = 8; i < 128; i += 8) {
    c0 = __fadd_rn(c0, __fmul_rn(x[j + i], x[j + i]));
    c1 = __fadd_rn(c1, __fmul_rn(x[128 + j + i], x[128 + j + i]));
  }
  #pragma unroll
  for (int off = 1; off <= 4; off <<= 1) {
    c0 = __fadd_rn(c0, __shfl_xor(c0, off));
    c1 = __fadd_rn(c1, __shfl_xor(c1, off));
  }
  if (j == 0) sc[row] = __fadd_rn(c0, c1);
}

// ---------------------------------------------------------------------------
// f16 MFMA score pass v5: no LDS in K-loop; A/B fragments straight from
// L2-resident global. Block 128x128, 4 waves 2x2, wave-tile 64x64.
// ---------------------------------------------------------------------------
__global__ __launch_bounds__(256, 2)
void k_mfma(const _Float16* __restrict__ Ah, const _Float16* __restrict__ Bh,
            const float* __restrict__ sc,
            float* __restrict__ pd1, float* __restrict__ pd2, int* __restrict__ pi1) {
  __shared__ float red1[128 * 2];
  __shared__ float red2[128 * 2];
  __shared__ int   redi[128 * 2];

  // XCD-aware swizzle: per-XCD m-slab (A-slab ~1 MB + B 4 MB ≈ per-XCD L2)
  const int idx = blockIdx.x;
  const int by  = (idx & 7) * 16 + ((idx >> 3) >> 6);   // 0..127
  const int bx  = (idx >> 3) & 63;                      // 0..63
  const int m0  = by * 128, n0 = bx * 128;

  const int tid  = threadIdx.x;
  const int w    = tid >> 6, lane = tid & 63;
  const int wy   = w >> 1, wx = w & 1;
  const int l15  = lane & 15, quad = lane >> 4;

  const _Float16* gA = Ah + (size_t)(m0 + wy * 64 + l15) * Dd + quad * 8;
  const _Float16* gB = Bh + (size_t)(n0 + wx * 64 + l15) * Dd + quad * 8;

  f32x4 acc[4][4];
  #pragma unroll
  for (int mi = 0; mi < 4; ++mi)
    #pragma unroll
    for (int ni = 0; ni < 4; ++ni)
      acc[mi][ni] = (f32x4){0.f, 0.f, 0.f, 0.f};

  #pragma unroll
  for (int kc = 0; kc < 4; ++kc) {
    f16x8 af[4][2], bf[4][2];
    #pragma unroll
    for (int mi = 0; mi < 4; ++mi)
      #pragma unroll
      for (int ks = 0; ks < 2; ++ks)
        af[mi][ks] = *(const f16x8*)(gA + (size_t)mi * 16 * Dd + kc * 64 + ks * 32);
    #pragma unroll
    for (int ni = 0; ni < 4; ++ni)
      #pragma unroll
      for (int ks = 0; ks < 2; ++ks)
        bf[ni][ks] = *(const f16x8*)(gB + (size_t)ni * 16 * Dd + kc * 64 + ks * 32);
    #pragma unroll
    for (int ks = 0; ks < 2; ++ks)
      #pragma unroll
      for (int mi = 0; mi < 4; ++mi)
        #pragma unroll
        for (int ni = 0; ni < 4; ++ni)
          acc[mi][ni] = __builtin_amdgcn_mfma_f32_16x16x32_f16(af[mi][ks], bf[ni][ks], acc[mi][ni], 0, 0, 0);
  }

  // ---- epilogue: per-row top-2 over this 128-code split ----
  float scv[4];
  #pragma unroll
  for (int ni = 0; ni < 4; ++ni) scv[ni] = sc[n0 + wx * 64 + ni * 16 + l15];

  float s1[16], s2[16]; int i1[16];
  #pragma unroll
  for (int mi = 0; mi < 4; ++mi)
    #pragma unroll
    for (int r = 0; r < 4; ++r) {
      const int q = mi * 4 + r;
      float a1 = INFINITY, a2 = INFINITY; int ai = 0x7fffffff;
      #pragma unroll
      for (int ni = 0; ni < 4; ++ni) {         // ni ascending -> k ascending
        const float sv = fmaf(-0.0078125f, acc[mi][ni][r], scv[ni]);  // -2/256
        const int   k  = n0 + wx * 64 + ni * 16 + l15;
        if (sv < a1) { a2 = a1; a1 = sv; ai = k; }
        else if (sv < a2) a2 = sv;
      }
      s1[q] = a1; s2[q] = a2; i1[q] = ai;
    }

  // merge across the 16 lanes of each quad (same rows, different cols)
  #pragma unroll
  for (int off = 1; off <= 8; off <<= 1)
    #pragma unroll
    for (int q = 0; q < 16; ++q) {
      const float o1 = __shfl_xor(s1[q], off);
      const float o2 = __shfl_xor(s2[q], off);
      const int   oi = __shfl_xor(i1[q], off);
      if (o1 < s1[q] || (o1 == s1[q] && oi < i1[q])) {
        s2[q] = fminf(s1[q], o2); s1[q] = o1; i1[q] = oi;
      } else s2[q] = fminf(s2[q], o1);
    }

  // cross-wave (wx) merge through LDS
  if (l15 == 0) {
    #pragma unroll
    for (int mi = 0; mi < 4; ++mi)
      #pragma unroll
      for (int r = 0; r < 4; ++r) {
        const int q  = mi * 4 + r;
        const int ml = wy * 64 + mi * 16 + quad * 4 + r;
        red1[ml * 2 + wx] = s1[q];
        red2[ml * 2 + wx] = s2[q];
        redi[ml * 2 + wx] = i1[q];
      }
  }
  __syncthreads();
  if (tid < 128) {
    float a1 = red1[tid * 2], a2 = red2[tid * 2]; int ai = redi[tid * 2];
    const float b1 = red1[tid * 2 + 1], b2 = red2[tid * 2 + 1];
    const int   bi = redi[tid * 2 + 1];
    if (b1 < a1 || (b1 == a1 && bi < ai)) { a2 = fminf(a1, b2); a1 = b1; ai = bi; }
    else a2 = fminf(a2, b1);
    const size_t o = (size_t)bx * Mm + (size_t)(m0 + tid);
    pd1[o] = a1; pd2[o] = a2; pi1[o] = ai;
  }
}

// ---------------------------------------------------------------------------
// combine the NSPL partials per row; flag near-ties for np rescan
// ---------------------------------------------------------------------------
__global__ void k_combine(const float* __restrict__ pd1, const float* __restrict__ pd2,
                          const int* __restrict__ pi1, int* __restrict__ idxf,
                          int* __restrict__ rescan_cnt, int* __restrict__ rlist,
                          float* __restrict__ outIdx) {
  const int m = blockIdx.x * blockDim.x + threadIdx.x;
  if (m >= Mm) return;
  float a1 = INFINITY, a2 = INFINITY; int ai = 0x7fffffff;
  for (int spl = 0; spl < NSPL; ++spl) {       // spl ascending -> k ascending
    const size_t o = (size_t)spl * Mm + m;
    const float b1 = pd1[o], b2 = pd2[o]; const int bi = pi1[o];
    if (b1 < a1 || (b1 == a1 && bi < ai)) { a2 = fminf(a1, b2); a1 = b1; ai = bi; }
    else a2 = fminf(a2, b1);
  }
  idxf[m]   = ai;
  outIdx[m] = (float)ai;
  if (a2 - a1 <= RESCAN_MARGIN) { const int p = atomicAdd(rescan_cnt, 1); rlist[p] = m; }
}

// ---------------------------------------------------------------------------
// gather flagged rows into compact zg; np norms; init packed minima
// ---------------------------------------------------------------------------
__global__ void k_gather(const float* __restrict__ z, const int* __restrict__ rescan_cnt,
                         const int* __restrict__ rlist, float* __restrict__ zg,
                         float* __restrict__ Ag, unsigned long long* __restrict__ pbrow) {
  __shared__ float zr[Dd];
  const int cnt = min(*rescan_cnt, ZG_CAP);
  for (int it = blockIdx.x; it < cnt; it += gridDim.x) {
    const int m = rlist[it];
    const int b = m / Tt, t = m & (Tt - 1);
    __syncthreads();
    zr[threadIdx.x] = z[(size_t)b * Dd * Tt + (size_t)threadIdx.x * Tt + t];
    __syncthreads();
    zg[(size_t)it * Dd + threadIdx.x] = zr[threadIdx.x];
    if (threadIdx.x == 0) { Ag[it] = np_sumsq256(zr); pbrow[it] = ~0ull; }
  }
}

// ---------------------------------------------------------------------------
// chunked np-faithful rescan: packed (orderable f32, idx) atomicMin per row
// ---------------------------------------------------------------------------
__global__ __launch_bounds__(256)
void k_rescan_part(const float* __restrict__ cb, const float* __restrict__ sc,
                   const int* __restrict__ rescan_cnt, const float* __restrict__ zg,
                   const float* __restrict__ Ag, unsigned long long* __restrict__ pbrow) {
  __shared__ float  cs[CHK * 257];
  __shared__ float  scs[CHK];
  __shared__ float  zf[Dd];
  __shared__ double pr[256];
  const int tid = threadIdx.x;
  const int cnt = min(*rescan_cnt, ZG_CAP);
  const int c = blockIdx.x >> 4;
  const int g = blockIdx.x & (GRP - 1);
  if (g >= cnt) return;
  const int k0 = c * CHK;
  for (int i = tid; i < CHK * Dd; i += 256) {
    const int code = i >> 8, d = i & 255;
    cs[code * 257 + d] = cb[(size_t)(k0 + code) * Dd + d];
  }
  if (tid < CHK) scs[tid] = sc[k0 + tid];
  const int code = tid & 31, seg = tid >> 5;
  __syncthreads();
  for (int it = g; it < cnt; it += GRP) {
    zf[tid] = zg[(size_t)it * Dd + tid];
    __syncthreads();
    const float* cp = &cs[code * 257 + seg * 32];
    const float* zp = &zf[seg * 32];
    double a0 = 0.0, a1 = 0.0, a2 = 0.0, a3 = 0.0;
    #pragma unroll
    for (int j = 0; j < 32; j += 4) {
      a0 = fma((double)cp[j+0], (double)zp[j+0], a0);
      a1 = fma((double)cp[j+1], (double)zp[j+1], a1);
      a2 = fma((double)cp[j+2], (double)zp[j+2], a2);
      a3 = fma((double)cp[j+3], (double)zp[j+3], a3);
    }
    pr[tid] = (a0 + a1) + (a2 + a3);
    __syncthreads();
    if (tid < CHK) {
      double M8 = 0.0;
      #pragma unroll
      for (int sg = 0; sg < 8; ++sg) M8 += pr[tid + sg * 32];
      const float M  = (float)M8;
      const float t1 = __fsub_rn(Ag[it], __fmul_rn(2.0f, M));
      const float dq = __fadd_rn(t1, scs[tid]);
      unsigned int fb = __float_as_uint(dq);
      fb = (fb & 0x80000000u) ? ~fb : (fb | 0x80000000u);
      unsigned long long pack = ((unsigned long long)fb << 32) | (unsigned)(k0 + tid);
      #pragma unroll
      for (int off = 16; off; off >>= 1) {
        const unsigned long long o = __shfl_xor(pack, off);
        if (o < pack) pack = o;
      }
      if (tid == 0) atomicMin(pbrow + it, pack);
    }
    __syncthreads();
  }
}

__global__ void k_rescan_final(const int* __restrict__ rescan_cnt, const int* __restrict__ rlist,
                               const unsigned long long* __restrict__ pbrow,
                               int* __restrict__ idxf, float* __restrict__ outIdx) {
  const int cnt = min(*rescan_cnt, ZG_CAP);
  const int it = blockIdx.x * blockDim.x + threadIdx.x;
  if (it < cnt) {
    const int idx = (int)(unsigned)(pbrow[it] & 0xFFFFFFFFull);
    const int m = rlist[it];
    idxf[m] = idx; outIdx[m] = (float)idx;
  }
}

// overflow fallback: normally 0 iterations
__global__ void k_rescan_slow(const float* __restrict__ z, const float* __restrict__ cb,
                              const float* __restrict__ sc,
                              const int* __restrict__ rescan_cnt, const int* __restrict__ rlist,
                              int* __restrict__ idxf, float* __restrict__ outIdx) {
  __shared__ float zrow[Dd];
  __shared__ float Ash;
  __shared__ float sval[256];
  __shared__ int   sidx[256];
  const int tid = threadIdx.x;
  const int cnt = *rescan_cnt;
  for (int it = ZG_CAP + blockIdx.x; it < cnt; it += gridDim.x) {
    const int m = rlist[it];
    const int b = m / Tt, t = m & (Tt - 1);
    __syncthreads();
    zrow[tid] = z[(size_t)b * Dd * Tt + (size_t)tid * Tt + t];
    __syncthreads();
    if (tid == 0) Ash = np_sumsq256(zrow);
    __syncthreads();
    const float A = Ash;
    float best = INFINITY; int bi = 0x7fffffff;
    for (int k = tid; k < Kk; k += 256) {
      const float* cr = cb + (size_t)k * Dd;
      double a0 = 0.0, a1 = 0.0, a2 = 0.0, a3 = 0.0;
      for (int d = 0; d < Dd; d += 4) {
        const float4 c4 = *(const float4*)(cr + d);
        a0 = fma((double)c4.x, (double)zrow[d+0], a0);
        a1 = fma((double)c4.y, (double)zrow[d+1], a1);
        a2 = fma((double)c4.z, (double)zrow[d+2], a2);
        a3 = fma((double)c4.w, (double)zrow[d+3], a3);
      }
      const float M  = (float)((a0 + a1) + (a2 + a3));
      const float t1 = __fsub_rn(A, __fmul_rn(2.0f, M));
      const float dq = __fadd_rn(t1, sc[k]);
      if (dq < best) { best = dq; bi = k; }
    }
    sval[tid] = best; sidx[tid] = bi;
    __syncthreads();
    for (int off = 128; off; off >>= 1) {
      if (tid < off) {
        if (sval[tid+off] < sval[tid] ||
            (sval[tid+off] == sval[tid] && sidx[tid+off] < sidx[tid])) {
          sval[tid] = sval[tid+off]; sidx[tid] = sidx[tid+off];
        }
      }
      __syncthreads();
    }
    if (tid == 0) { idxf[m] = sidx[0]; outIdx[m] = (float)sidx[0]; }
    __syncthreads();
  }
}

// ---------------------------------------------------------------------------
// fused gather + transpose + STE + loss: out[b][d][t] = z + (cb[idx] - z)
// ---------------------------------------------------------------------------
__global__ void k_out(const float* __restrict__ z, const float* __restrict__ cb,
                      const int* __restrict__ idxf,
                      float* __restrict__ outZ, double* __restrict__ loss_accum) {
  __shared__ float tile[64][65];          // [d][t]
  const int tid = threadIdx.x;
  const int bidx = blockIdx.x;            // 8 * 4 * 32 = 1024
  const int b  = bidx >> 7;
  const int dt = (bidx >> 5) & 3;
  const int tt = bidx & 31;
  const int d0 = dt * 64, t0 = tt * 64;
  // phase 1: gather cb rows coalesced (4 threads per row)
  {
    const int r = tid >> 2, seg = tid & 3;
    const int idx = idxf[b * Tt + t0 + r];
    const float* src = cb + (size_t)idx * Dd + d0 + seg * 16;
    #pragma unroll
    for (int q4 = 0; q4 < 4; ++q4) {
      const float4 v = *(const float4*)(src + q4 * 4);
      tile[seg * 16 + q4 * 4 + 0][r] = v.x;
      tile[seg * 16 + q4 * 4 + 1][r] = v.y;
      tile[seg * 16 + q4 * 4 + 2][r] = v.z;
      tile[seg * 16 + q4 * 4 + 3][r] = v.w;
    }
  }
  __syncthreads();
  // phase 2: write out along t, fuse STE + loss
  const float* zbase = z + ((size_t)b * Dd + d0) * Tt + t0;
  float*       obase = outZ + ((size_t)b * Dd + d0) * Tt + t0;
  double ls = 0.0;
  #pragma unroll
  for (int p = 0; p < 4; ++p) {
    const int d  = p * 16 + (tid >> 4);
    const int t4 = (tid & 15) * 4;
    const float4 zv = *(const float4*)(zbase + (size_t)d * Tt + t4);
    const float q0 = tile[d][t4+0], q1 = tile[d][t4+1];
    const float q2 = tile[d][t4+2], q3 = tile[d][t4+3];
    const float r0 = q0 - zv.x, r1 = q1 - zv.y, r2 = q2 - zv.z, r3 = q3 - zv.w;
    float4 o;
    o.x = zv.x + r0; o.y = zv.y + r1; o.z = zv.z + r2; o.w = zv.w + r3;
    *(float4*)(obase + (size_t)d * Tt + t4) = o;
    ls += (double)r0*r0 + (double)r1*r1 + (double)r2*r2 + (double)r3*r3;
  }
  #pragma unroll
  for (int off = 32; off; off >>= 1) ls += __shfl_down(ls, off);
  if ((tid & 63) == 0) atomicAdd(loss_accum, ls);
}

__global__ void k_finalize(const double* __restrict__ loss_accum, float* __restrict__ outLoss) {
  const double mean = *loss_accum / (double)((size_t)Bz * Dd * Tt);
  *outLoss = (float)(mean + 0.1 * mean);
}

// ---------------------------------------------------------------------------
extern "C" void kernel_launch(void* const* d_in, const int* in_sizes, int n_in,
                              void* d_out, int out_size, void* d_ws, size_t ws_size,
                              hipStream_t stream) {
  (void)in_sizes; (void)n_in; (void)out_size; (void)ws_size;
  const float* z  = (const float*)d_in[0];   // (B, D, T) fp32
  const float* cb = (const float*)d_in[1];   // (K, D)    fp32

  float* outZ    = (float*)d_out;
  float* outIdx  = outZ + (size_t)Bz * Dd * Tt;
  float* outLoss = outIdx + Mm;

  char* w = (char*)d_ws;
  double*    loss_accum = (double*)w;    w += 16;
  int*       rescan_cnt = (int*)w;       w += 16;
  int*       rlist      = (int*)w;       w += sizeof(int)   * Mm;
  int*       idxf       = (int*)w;       w += sizeof(int)   * Mm;
  float*     sc         = (float*)w;     w += sizeof(float) * Kk;
  _Float16*  Ah         = (_Float16*)w;  w += sizeof(_Float16) * (size_t)Mm * Dd;
  _Float16*  Bh         = (_Float16*)w;  w += sizeof(_Float16) * (size_t)Kk * Dd;
  float*     zg         = (float*)w;     w += sizeof(float) * (size_t)ZG_CAP * Dd;
  float*     Ag         = (float*)w;     w += sizeof(float) * ZG_CAP;
  unsigned long long* pbrow = (unsigned long long*)w; w += sizeof(unsigned long long) * ZG_CAP;
  float*     pd1        = (float*)w;     w += sizeof(float) * (size_t)NSPL * Mm;
  float*     pd2        = (float*)w;     w += sizeof(float) * (size_t)NSPL * Mm;
  int*       pi1        = (int*)w;       /* total ~55 MB */

  k_cast_z      <<<dim3(1024), 256, 0, stream>>>(z, Ah);
  k_cast_cb     <<<dim3((Kk * Dd / 8) / 256), 256, 0, stream>>>(cb, Bh);
  k_prep        <<<dim3(Kk * 8 / 256), 256, 0, stream>>>(cb, sc, loss_accum, rescan_cnt);
  k_mfma        <<<dim3((Mm / 128) * NSPL), 256, 0, stream>>>(Ah, Bh, sc, pd1, pd2, pi1);
  k_combine     <<<dim3(Mm / 256), 256, 0, stream>>>(pd1, pd2, pi1, idxf, rescan_cnt, rlist, outIdx);
  k_gather      <<<dim3(256), 256, 0, stream>>>(z, rescan_cnt, rlist, zg, Ag, pbrow);
  k_rescan_part <<<dim3((Kk / CHK) * GRP), 256, 0, stream>>>(cb, sc, rescan_cnt, zg, Ag, pbrow);
  k_rescan_slow <<<dim3(64), 256, 0, stream>>>(z, cb, sc, rescan_cnt, rlist, idxf, outIdx);
  k_rescan_final<<<dim3(ZG_CAP / 256), 256, 0, stream>>>(rescan_cnt, rlist, pbrow, idxf, outIdx);
  k_out         <<<dim3(1024), 256, 0, stream>>>(z, cb, idxf, outZ, loss_accum);
  k_finalize    <<<dim3(1), 1, 0, stream>>>(loss_accum, outLoss);
}

// Round 7
// 634.364 us; speedup vs baseline: 2.6387x; 1.0661x over previous
//
#include <hip/hip_runtime.h>
#include <hip/hip_bf16.h>
#include <float.h>
#include <math.h>

#define Bz 8
#define Dd 256
#define Tt 2048
#define Kk 8192
#define Mm (Bz*Tt)          // 16384 rows (b*T + t)

// Scorer: block = 64 rows x 1024 codes (nt-loop of 8 x 128), 4 waves 2m x 2n,
// wave-tile 32m x 64n per nt. A register-persistent, B double-buffered regs,
// no LDS in K-loop, operands straight from L2-resident Ah/Bh.
#define NSPL 8

// Rescan chunking
#define CHK 32
#define GRP 16
#define ZG_CAP 4096

// Margin: covers f16 fast-pass score error + np fp32 quantization straddle
#define RESCAN_MARGIN 6e-4f

typedef __attribute__((ext_vector_type(8))) _Float16 f16x8;
typedef __attribute__((ext_vector_type(4))) float    f32x4;

// ---------------------------------------------------------------------------
// numpy-faithful pairwise sum of squares (blocksize-128 pairwise, 8 accums)
// ---------------------------------------------------------------------------
__device__ __forceinline__ float np_sumsq128(const float* __restrict__ x) {
  float r0 = __fmul_rn(x[0], x[0]);
  float r1 = __fmul_rn(x[1], x[1]);
  float r2 = __fmul_rn(x[2], x[2]);
  float r3 = __fmul_rn(x[3], x[3]);
  float r4 = __fmul_rn(x[4], x[4]);
  float r5 = __fmul_rn(x[5], x[5]);
  float r6 = __fmul_rn(x[6], x[6]);
  float r7 = __fmul_rn(x[7], x[7]);
  for (int i = 8; i < 128; i += 8) {
    r0 = __fadd_rn(r0, __fmul_rn(x[i+0], x[i+0]));
    r1 = __fadd_rn(r1, __fmul_rn(x[i+1], x[i+1]));
    r2 = __fadd_rn(r2, __fmul_rn(x[i+2], x[i+2]));
    r3 = __fadd_rn(r3, __fmul_rn(x[i+3], x[i+3]));
    r4 = __fadd_rn(r4, __fmul_rn(x[i+4], x[i+4]));
    r5 = __fadd_rn(r5, __fmul_rn(x[i+5], x[i+5]));
    r6 = __fadd_rn(r6, __fmul_rn(x[i+6], x[i+6]));
    r7 = __fadd_rn(r7, __fmul_rn(x[i+7], x[i+7]));
  }
  return __fadd_rn(__fadd_rn(__fadd_rn(r0, r1), __fadd_rn(r2, r3)),
                   __fadd_rn(__fadd_rn(r4, r5), __fadd_rn(r6, r7)));
}
__device__ __forceinline__ float np_sumsq256(const float* __restrict__ x) {
  return __fadd_rn(np_sumsq128(x), np_sumsq128(x + 128));
}

// ---------------------------------------------------------------------------
// transpose-cast z (B,D,T) f32 -> Ah (M, D) f16
// ---------------------------------------------------------------------------
__global__ void k_cast_z(const float* __restrict__ z, _Float16* __restrict__ Ah) {
  __shared__ _Float16 tile[64][64 + 8];
  const int tid = threadIdx.x;
  const int bidx = blockIdx.x;            // 8 * 4 * 32 = 1024
  const int b  = bidx >> 7;
  const int dt = (bidx >> 5) & 3;
  const int tt = bidx & 31;
  const int d0 = dt * 64, t0 = tt * 64;
  const float* zb = z + ((size_t)b * Dd + d0) * Tt + t0;
  #pragma unroll
  for (int p = 0; p < 4; ++p) {
    const int d  = p * 16 + (tid >> 4);
    const int tl = (tid & 15) * 4;
    const float4 v = *(const float4*)(zb + (size_t)d * Tt + tl);
    tile[tl+0][d] = (_Float16)v.x;
    tile[tl+1][d] = (_Float16)v.y;
    tile[tl+2][d] = (_Float16)v.z;
    tile[tl+3][d] = (_Float16)v.w;
  }
  __syncthreads();
  const int r = tid >> 2, seg = tid & 3;
  const int m = b * Tt + t0 + r;
  int4* dst = (int4*)(Ah + (size_t)m * Dd + d0 + seg * 16);
  const int4* srcv = (const int4*)(&tile[r][seg * 16]);
  dst[0] = srcv[0];
  dst[1] = srcv[1];
}

// ---------------------------------------------------------------------------
// cast codebook f32 -> f16, prescaled by 256 (avoids f16 subnormals)
// ---------------------------------------------------------------------------
__global__ void k_cast_cb(const float* __restrict__ cb, _Float16* __restrict__ Bh) {
  const size_t g = (size_t)blockIdx.x * blockDim.x + threadIdx.x;
  const float4 v0 = *(const float4*)(cb + g * 8);
  const float4 v1 = *(const float4*)(cb + g * 8 + 4);
  f16x8 o;
  o[0] = (_Float16)(v0.x * 256.f); o[1] = (_Float16)(v0.y * 256.f);
  o[2] = (_Float16)(v0.z * 256.f); o[3] = (_Float16)(v0.w * 256.f);
  o[4] = (_Float16)(v1.x * 256.f); o[5] = (_Float16)(v1.y * 256.f);
  o[6] = (_Float16)(v1.z * 256.f); o[7] = (_Float16)(v1.w * 256.f);
  *(f16x8*)(Bh + g * 8) = o;
}

// ---------------------------------------------------------------------------
// np-faithful codebook norms, wave-parallel (8 lanes own np's 8 acc chains)
// ---------------------------------------------------------------------------
__global__ void k_prep(const float* __restrict__ cb, float* __restrict__ sc,
                       double* __restrict__ loss_accum, int* __restrict__ rescan_cnt) {
  const int gid = blockIdx.x * blockDim.x + threadIdx.x;
  if (gid == 0) { *loss_accum = 0.0; *rescan_cnt = 0; }
  const int lane = gid & 63;
  const int j = lane & 7, sub = lane >> 3;
  const int row = (gid >> 6) * 8 + sub;
  if (row >= Kk) return;
  const float* x = cb + (size_t)row * Dd;
  float c0 = __fmul_rn(x[j], x[j]);
  float c1 = __fmul_rn(x[128 + j], x[128 + j]);
  #pragma unroll
  for (int i = 8; i < 128; i += 8) {
    c0 = __fadd_rn(c0, __fmul_rn(x[j + i], x[j + i]));
    c1 = __fadd_rn(c1, __fmul_rn(x[128 + j + i], x[128 + j + i]));
  }
  #pragma unroll
  for (int off = 1; off <= 4; off <<= 1) {
    c0 = __fadd_rn(c0, __shfl_xor(c0, off));
    c1 = __fadd_rn(c1, __shfl_xor(c1, off));
  }
  if (j == 0) sc[row] = __fadd_rn(c0, c1);
}

// ---------------------------------------------------------------------------
// f16 MFMA score pass v6: 64 rows x 1024 codes per block; A persistent in
// VGPRs (all static indices), B reg double-buffer w/ prefetch, fused top-2.
// ---------------------------------------------------------------------------
#define LOADBF(SET, BASE, KC) do {                                            \
    const _Float16* _p = (BASE) + (KC) * 64;                                  \
    bf[SET][0][0] = *(const f16x8*)(_p);                                      \
    bf[SET][0][1] = *(const f16x8*)(_p + 32);                                 \
    bf[SET][1][0] = *(const f16x8*)(_p + 16 * Dd);                            \
    bf[SET][1][1] = *(const f16x8*)(_p + 16 * Dd + 32);                       \
    bf[SET][2][0] = *(const f16x8*)(_p + 32 * Dd);                            \
    bf[SET][2][1] = *(const f16x8*)(_p + 32 * Dd + 32);                       \
    bf[SET][3][0] = *(const f16x8*)(_p + 48 * Dd);                            \
    bf[SET][3][1] = *(const f16x8*)(_p + 48 * Dd + 32);                       \
  } while (0)

#define MFMA_KC(SET, KC) do {                                                 \
    _Pragma("unroll")                                                         \
    for (int ks = 0; ks < 2; ++ks) {                                          \
      _Pragma("unroll")                                                       \
      for (int mi = 0; mi < 2; ++mi) {                                        \
        _Pragma("unroll")                                                     \
        for (int ni = 0; ni < 4; ++ni)                                        \
          acc[mi][ni] = __builtin_amdgcn_mfma_f32_16x16x32_f16(               \
              af[KC][ks][mi], bf[SET][ni][ks], acc[mi][ni], 0, 0, 0);         \
      }                                                                       \
    }                                                                         \
  } while (0)

__global__ __launch_bounds__(256, 2)
void k_mfma(const _Float16* __restrict__ Ah, const _Float16* __restrict__ Bh,
            const float* __restrict__ sc,
            float* __restrict__ pd1, float* __restrict__ pd2, int* __restrict__ pi1) {
  __shared__ float red1[64 * 2];
  __shared__ float red2[64 * 2];
  __shared__ int   redi[64 * 2];

  const int tid = threadIdx.x;
  const int bx  = blockIdx.x & 7;        // n-split -> XCD-resident B-slab
  const int by  = blockIdx.x >> 3;       // 0..255
  const int m0  = by * 64, n0 = bx * 1024;
  const int w   = tid >> 6, lane = tid & 63;
  const int wy  = w >> 1, wx = w & 1;
  const int l15 = lane & 15, quad = lane >> 4;

  // ---- A: 64 VGPRs, persistent, statically indexed everywhere
  f16x8 af[4][2][2];
  {
    const _Float16* gA = Ah + (size_t)(m0 + wy * 32 + l15) * Dd + quad * 8;
    #pragma unroll
    for (int kc = 0; kc < 4; ++kc)
      #pragma unroll
      for (int ks = 0; ks < 2; ++ks)
        #pragma unroll
        for (int mi = 0; mi < 2; ++mi)
          af[kc][ks][mi] = *(const f16x8*)(gA + (size_t)mi * 16 * Dd + kc * 64 + ks * 32);
  }

  const _Float16* gB0 = Bh + (size_t)(n0 + wx * 64 + l15) * Dd + quad * 8;

  f16x8 bf[2][4][2];
  f32x4 acc[2][4];
  #pragma unroll
  for (int mi = 0; mi < 2; ++mi)
    #pragma unroll
    for (int ni = 0; ni < 4; ++ni)
      acc[mi][ni] = (f32x4){0.f, 0.f, 0.f, 0.f};

  float s1[8], s2[8]; int i1[8];
  #pragma unroll
  for (int q = 0; q < 8; ++q) { s1[q] = INFINITY; s2[q] = INFINITY; i1[q] = 0x7fffffff; }

  LOADBF(0, gB0, 0);                       // nt=0, kc=0

  for (int nt = 0; nt < 8; ++nt) {
    const _Float16* gBc = gB0 + (size_t)nt * 128 * Dd;
    const _Float16* gBn = gB0 + (size_t)((nt + 1) & 7) * 128 * Dd;  // wrap: dummy ld
    float scv[4];
    #pragma unroll
    for (int ni = 0; ni < 4; ++ni)
      scv[ni] = sc[n0 + nt * 128 + wx * 64 + ni * 16 + l15];

    LOADBF(1, gBc, 1);
    MFMA_KC(0, 0);
    LOADBF(0, gBc, 2);
    MFMA_KC(1, 1);
    LOADBF(1, gBc, 3);
    MFMA_KC(0, 2);
    LOADBF(0, gBn, 0);                     // prefetch next nt's kc0
    MFMA_KC(1, 3);

    // fold this n-tile into per-thread top-2 (k ascending across nt, ni)
    #pragma unroll
    for (int mi = 0; mi < 2; ++mi)
      #pragma unroll
      for (int r = 0; r < 4; ++r) {
        const int q = mi * 4 + r;
        #pragma unroll
        for (int ni = 0; ni < 4; ++ni) {
          const float sv = fmaf(-0.0078125f, acc[mi][ni][r], scv[ni]);  // -2/256
          const int   k  = n0 + nt * 128 + wx * 64 + ni * 16 + l15;
          if (sv < s1[q]) { s2[q] = s1[q]; s1[q] = sv; i1[q] = k; }
          else if (sv < s2[q]) s2[q] = sv;
          acc[mi][ni][r] = 0.f;
        }
      }
  }

  // ---- merge across the 16 lanes of each quad (same rows, different cols)
  #pragma unroll
  for (int off = 1; off <= 8; off <<= 1)
    #pragma unroll
    for (int q = 0; q < 8; ++q) {
      const float o1 = __shfl_xor(s1[q], off);
      const float o2 = __shfl_xor(s2[q], off);
      const int   oi = __shfl_xor(i1[q], off);
      if (o1 < s1[q] || (o1 == s1[q] && oi < i1[q])) {
        s2[q] = fminf(s1[q], o2); s1[q] = o1; i1[q] = oi;
      } else s2[q] = fminf(s2[q], o1);
    }

  // ---- cross-wave (wx) merge through LDS
  if (l15 == 0) {
    #pragma unroll
    for (int mi = 0; mi < 2; ++mi)
      #pragma unroll
      for (int r = 0; r < 4; ++r) {
        const int q  = mi * 4 + r;
        const int ml = wy * 32 + mi * 16 + quad * 4 + r;
        red1[ml * 2 + wx] = s1[q];
        red2[ml * 2 + wx] = s2[q];
        redi[ml * 2 + wx] = i1[q];
      }
  }
  __syncthreads();
  if (tid < 64) {
    float a1 = red1[tid * 2], a2 = red2[tid * 2]; int ai = redi[tid * 2];
    const float b1 = red1[tid * 2 + 1], b2 = red2[tid * 2 + 1];
    const int   bi = redi[tid * 2 + 1];
    if (b1 < a1 || (b1 == a1 && bi < ai)) { a2 = fminf(a1, b2); a1 = b1; ai = bi; }
    else a2 = fminf(a2, b1);
    const size_t o = (size_t)bx * Mm + (size_t)(m0 + tid);
    pd1[o] = a1; pd2[o] = a2; pi1[o] = ai;
  }
}

// ---------------------------------------------------------------------------
// combine the NSPL partials per row; flag near-ties for np rescan
// ---------------------------------------------------------------------------
__global__ void k_combine(const float* __restrict__ pd1, const float* __restrict__ pd2,
                          const int* __restrict__ pi1, int* __restrict__ idxf,
                          int* __restrict__ rescan_cnt, int* __restrict__ rlist,
                          float* __restrict__ outIdx) {
  const int m = blockIdx.x * blockDim.x + threadIdx.x;
  if (m >= Mm) return;
  float a1 = INFINITY, a2 = INFINITY; int ai = 0x7fffffff;
  #pragma unroll
  for (int spl = 0; spl < NSPL; ++spl) {       // spl ascending -> k ascending
    const size_t o = (size_t)spl * Mm + m;
    const float b1 = pd1[o], b2 = pd2[o]; const int bi = pi1[o];
    if (b1 < a1 || (b1 == a1 && bi < ai)) { a2 = fminf(a1, b2); a1 = b1; ai = bi; }
    else a2 = fminf(a2, b1);
  }
  idxf[m]   = ai;
  outIdx[m] = (float)ai;
  if (a2 - a1 <= RESCAN_MARGIN) { const int p = atomicAdd(rescan_cnt, 1); rlist[p] = m; }
}

// ---------------------------------------------------------------------------
// gather flagged rows into compact zg; np norms; init packed minima
// ---------------------------------------------------------------------------
__global__ void k_gather(const float* __restrict__ z, const int* __restrict__ rescan_cnt,
                         const int* __restrict__ rlist, float* __restrict__ zg,
                         float* __restrict__ Ag, unsigned long long* __restrict__ pbrow) {
  __shared__ float zr[Dd];
  const int cnt = min(*rescan_cnt, ZG_CAP);
  for (int it = blockIdx.x; it < cnt; it += gridDim.x) {
    const int m = rlist[it];
    const int b = m / Tt, t = m & (Tt - 1);
    __syncthreads();
    zr[threadIdx.x] = z[(size_t)b * Dd * Tt + (size_t)threadIdx.x * Tt + t];
    __syncthreads();
    zg[(size_t)it * Dd + threadIdx.x] = zr[threadIdx.x];
    if (threadIdx.x == 0) { Ag[it] = np_sumsq256(zr); pbrow[it] = ~0ull; }
  }
}

// ---------------------------------------------------------------------------
// chunked np-faithful rescan: packed (orderable f32, idx) atomicMin per row
// ---------------------------------------------------------------------------
__global__ __launch_bounds__(256)
void k_rescan_part(const float* __restrict__ cb, const float* __restrict__ sc,
                   const int* __restrict__ rescan_cnt, const float* __restrict__ zg,
                   const float* __restrict__ Ag, unsigned long long* __restrict__ pbrow) {
  __shared__ float  cs[CHK * 257];
  __shared__ float  scs[CHK];
  __shared__ float  zf[Dd];
  __shared__ double pr[256];
  const int tid = threadIdx.x;
  const int cnt = min(*rescan_cnt, ZG_CAP);
  const int c = blockIdx.x >> 4;
  const int g = blockIdx.x & (GRP - 1);
  if (g >= cnt) return;
  const int k0 = c * CHK;
  for (int i = tid; i < CHK * Dd; i += 256) {
    const int code = i >> 8, d = i & 255;
    cs[code * 257 + d] = cb[(size_t)(k0 + code) * Dd + d];
  }
  if (tid < CHK) scs[tid] = sc[k0 + tid];
  const int code = tid & 31, seg = tid >> 5;
  __syncthreads();
  for (int it = g; it < cnt; it += GRP) {
    zf[tid] = zg[(size_t)it * Dd + tid];
    __syncthreads();
    const float* cp = &cs[code * 257 + seg * 32];
    const float* zp = &zf[seg * 32];
    double a0 = 0.0, a1 = 0.0, a2 = 0.0, a3 = 0.0;
    #pragma unroll
    for (int j = 0; j < 32; j += 4) {
      a0 = fma((double)cp[j+0], (double)zp[j+0], a0);
      a1 = fma((double)cp[j+1], (double)zp[j+1], a1);
      a2 = fma((double)cp[j+2], (double)zp[j+2], a2);
      a3 = fma((double)cp[j+3], (double)zp[j+3], a3);
    }
    pr[tid] = (a0 + a1) + (a2 + a3);
    __syncthreads();
    if (tid < CHK) {
      double M8 = 0.0;
      #pragma unroll
      for (int sg = 0; sg < 8; ++sg) M8 += pr[tid + sg * 32];
      const float M  = (float)M8;
      const float t1 = __fsub_rn(Ag[it], __fmul_rn(2.0f, M));
      const float dq = __fadd_rn(t1, scs[tid]);
      unsigned int fb = __float_as_uint(dq);
      fb = (fb & 0x80000000u) ? ~fb : (fb | 0x80000000u);
      unsigned long long pack = ((unsigned long long)fb << 32) | (unsigned)(k0 + tid);
      #pragma unroll
      for (int off = 16; off; off >>= 1) {
        const unsigned long long o = __shfl_xor(pack, off);
        if (o < pack) pack = o;
      }
      if (tid == 0) atomicMin(pbrow + it, pack);
    }
    __syncthreads();
  }
}

__global__ void k_rescan_final(const int* __restrict__ rescan_cnt, const int* __restrict__ rlist,
                               const unsigned long long* __restrict__ pbrow,
                               int* __restrict__ idxf, float* __restrict__ outIdx) {
  const int cnt = min(*rescan_cnt, ZG_CAP);
  const int it = blockIdx.x * blockDim.x + threadIdx.x;
  if (it < cnt) {
    const int idx = (int)(unsigned)(pbrow[it] & 0xFFFFFFFFull);
    const int m = rlist[it];
    idxf[m] = idx; outIdx[m] = (float)idx;
  }
}

// overflow fallback: normally 0 iterations
__global__ void k_rescan_slow(const float* __restrict__ z, const float* __restrict__ cb,
                              const float* __restrict__ sc,
                              const int* __restrict__ rescan_cnt, const int* __restrict__ rlist,
                              int* __restrict__ idxf, float* __restrict__ outIdx) {
  __shared__ float zrow[Dd];
  __shared__ float Ash;
  __shared__ float sval[256];
  __shared__ int   sidx[256];
  const int tid = threadIdx.x;
  const int cnt = *rescan_cnt;
  for (int it = ZG_CAP + blockIdx.x; it < cnt; it += gridDim.x) {
    const int m = rlist[it];
    const int b = m / Tt, t = m & (Tt - 1);
    __syncthreads();
    zrow[tid] = z[(size_t)b * Dd * Tt + (size_t)tid * Tt + t];
    __syncthreads();
    if (tid == 0) Ash = np_sumsq256(zrow);
    __syncthreads();
    const float A = Ash;
    float best = INFINITY; int bi = 0x7fffffff;
    for (int k = tid; k < Kk; k += 256) {
      const float* cr = cb + (size_t)k * Dd;
      double a0 = 0.0, a1 = 0.0, a2 = 0.0, a3 = 0.0;
      for (int d = 0; d < Dd; d += 4) {
        const float4 c4 = *(const float4*)(cr + d);
        a0 = fma((double)c4.x, (double)zrow[d+0], a0);
        a1 = fma((double)c4.y, (double)zrow[d+1], a1);
        a2 = fma((double)c4.z, (double)zrow[d+2], a2);
        a3 = fma((double)c4.w, (double)zrow[d+3], a3);
      }
      const float M  = (float)((a0 + a1) + (a2 + a3));
      const float t1 = __fsub_rn(A, __fmul_rn(2.0f, M));
      const float dq = __fadd_rn(t1, sc[k]);
      if (dq < best) { best = dq; bi = k; }
    }
    sval[tid] = best; sidx[tid] = bi;
    __syncthreads();
    for (int off = 128; off; off >>= 1) {
      if (tid < off) {
        if (sval[tid+off] < sval[tid] ||
            (sval[tid+off] == sval[tid] && sidx[tid+off] < sidx[tid])) {
          sval[tid] = sval[tid+off]; sidx[tid] = sidx[tid+off];
        }
      }
      __syncthreads();
    }
    if (tid == 0) { idxf[m] = sidx[0]; outIdx[m] = (float)sidx[0]; }
    __syncthreads();
  }
}

// ---------------------------------------------------------------------------
// fused gather + transpose + STE + loss: out[b][d][t] = z + (cb[idx] - z)
// ---------------------------------------------------------------------------
__global__ void k_out(const float* __restrict__ z, const float* __restrict__ cb,
                      const int* __restrict__ idxf,
                      float* __restrict__ outZ, double* __restrict__ loss_accum) {
  __shared__ float tile[64][65];          // [d][t]
  const int tid = threadIdx.x;
  const int bidx = blockIdx.x;            // 8 * 4 * 32 = 1024
  const int b  = bidx >> 7;
  const int dt = (bidx >> 5) & 3;
  const int tt = bidx & 31;
  const int d0 = dt * 64, t0 = tt * 64;
  // phase 1: gather cb rows coalesced (4 threads per row)
  {
    const int r = tid >> 2, seg = tid & 3;
    const int idx = idxf[b * Tt + t0 + r];
    const float* src = cb + (size_t)idx * Dd + d0 + seg * 16;
    #pragma unroll
    for (int q4 = 0; q4 < 4; ++q4) {
      const float4 v = *(const float4*)(src + q4 * 4);
      tile[seg * 16 + q4 * 4 + 0][r] = v.x;
      tile[seg * 16 + q4 * 4 + 1][r] = v.y;
      tile[seg * 16 + q4 * 4 + 2][r] = v.z;
      tile[seg * 16 + q4 * 4 + 3][r] = v.w;
    }
  }
  __syncthreads();
  // phase 2: write out along t, fuse STE + loss
  const float* zbase = z + ((size_t)b * Dd + d0) * Tt + t0;
  float*       obase = outZ + ((size_t)b * Dd + d0) * Tt + t0;
  double ls = 0.0;
  #pragma unroll
  for (int p = 0; p < 4; ++p) {
    const int d  = p * 16 + (tid >> 4);
    const int t4 = (tid & 15) * 4;
    const float4 zv = *(const float4*)(zbase + (size_t)d * Tt + t4);
    const float q0 = tile[d][t4+0], q1 = tile[d][t4+1];
    const float q2 = tile[d][t4+2], q3 = tile[d][t4+3];
    const float r0 = q0 - zv.x, r1 = q1 - zv.y, r2 = q2 - zv.z, r3 = q3 - zv.w;
    float4 o;
    o.x = zv.x + r0; o.y = zv.y + r1; o.z = zv.z + r2; o.w = zv.w + r3;
    *(float4*)(obase + (size_t)d * Tt + t4) = o;
    ls += (double)r0*r0 + (double)r1*r1 + (double)r2*r2 + (double)r3*r3;
  }
  #pragma unroll
  for (int off = 32; off; off >>= 1) ls += __shfl_down(ls, off);
  if ((tid & 63) == 0) atomicAdd(loss_accum, ls);
}

__global__ void k_finalize(const double* __restrict__ loss_accum, float* __restrict__ outLoss) {
  const double mean = *loss_accum / (double)((size_t)Bz * Dd * Tt);
  *outLoss = (float)(mean + 0.1 * mean);
}

// ---------------------------------------------------------------------------
extern "C" void kernel_launch(void* const* d_in, const int* in_sizes, int n_in,
                              void* d_out, int out_size, void* d_ws, size_t ws_size,
                              hipStream_t stream) {
  (void)in_sizes; (void)n_in; (void)out_size; (void)ws_size;
  const float* z  = (const float*)d_in[0];   // (B, D, T) fp32
  const float* cb = (const float*)d_in[1];   // (K, D)    fp32

  float* outZ    = (float*)d_out;
  float* outIdx  = outZ + (size_t)Bz * Dd * Tt;
  float* outLoss = outIdx + Mm;

  char* w = (char*)d_ws;
  double*    loss_accum = (double*)w;    w += 16;
  int*       rescan_cnt = (int*)w;       w += 16;
  int*       rlist      = (int*)w;       w += sizeof(int)   * Mm;
  int*       idxf       = (int*)w;       w += sizeof(int)   * Mm;
  float*     sc         = (float*)w;     w += sizeof(float) * Kk;
  _Float16*  Ah         = (_Float16*)w;  w += sizeof(_Float16) * (size_t)Mm * Dd;
  _Float16*  Bh         = (_Float16*)w;  w += sizeof(_Float16) * (size_t)Kk * Dd;
  float*     zg         = (float*)w;     w += sizeof(float) * (size_t)ZG_CAP * Dd;
  float*     Ag         = (float*)w;     w += sizeof(float) * ZG_CAP;
  unsigned long long* pbrow = (unsigned long long*)w; w += sizeof(unsigned long long) * ZG_CAP;
  float*     pd1        = (float*)w;     w += sizeof(float) * (size_t)NSPL * Mm;
  float*     pd2        = (float*)w;     w += sizeof(float) * (size_t)NSPL * Mm;
  int*       pi1        = (int*)w;       /* total ~24 MB */

  k_cast_z      <<<dim3(1024), 256, 0, stream>>>(z, Ah);
  k_cast_cb     <<<dim3((Kk * Dd / 8) / 256), 256, 0, stream>>>(cb, Bh);
  k_prep        <<<dim3(Kk * 8 / 256), 256, 0, stream>>>(cb, sc, loss_accum, rescan_cnt);
  k_mfma        <<<dim3((Mm / 64) * NSPL), 256, 0, stream>>>(Ah, Bh, sc, pd1, pd2, pi1);
  k_combine     <<<dim3(Mm / 256), 256, 0, stream>>>(pd1, pd2, pi1, idxf, rescan_cnt, rlist, outIdx);
  k_gather      <<<dim3(256), 256, 0, stream>>>(z, rescan_cnt, rlist, zg, Ag, pbrow);
  k_rescan_part <<<dim3((Kk / CHK) * GRP), 256, 0, stream>>>(cb, sc, rescan_cnt, zg, Ag, pbrow);
  k_rescan_slow <<<dim3(64), 256, 0, stream>>>(z, cb, sc, rescan_cnt, rlist, idxf, outIdx);
  k_rescan_final<<<dim3(ZG_CAP / 256), 256, 0, stream>>>(rescan_cnt, rlist, pbrow, idxf, outIdx);
  k_out         <<<dim3(1024), 256, 0, stream>>>(z, cb, idxf, outZ, loss_accum);
  k_finalize    <<<dim3(1), 1, 0, stream>>>(loss_accum, outLoss);
}